// Round 12
// baseline (1425.337 us; speedup 1.0000x reference)
//
#include <hip/hip_runtime.h>
#include <math.h>

// ---- problem constants ----
#define D_      1024
#define DH_     64
#define H_      8
#define INNER_  512
#define L_      6
#define NL_     64
#define FF_     4096
#define B_      4
#define T_      8
#define FV_     1024          // F*V
#define BT_     32            // B*T
#define MROWS_  32768         // BT*FV
#define NKV_    1088          // FV + NL
#define KVROWS_ 34816         // BT*NKV
#define ZB_     256           // BT*H

typedef __bf16 bf16;
typedef __bf16 bf16x8 __attribute__((ext_vector_type(8)));
typedef __bf16 bf16x4 __attribute__((ext_vector_type(4)));
typedef float  f32x4  __attribute__((ext_vector_type(4)));

#define BARRIER() { asm volatile("" ::: "memory"); __builtin_amdgcn_s_barrier(); asm volatile("" ::: "memory"); }
// end-of-phase (pipelined-frag schedule): pin ds_reads above, drain, barrier.
#define ENDPH() { __builtin_amdgcn_sched_barrier(0); asm volatile("s_waitcnt lgkmcnt(0)"); __builtin_amdgcn_sched_barrier(0); BARRIER(); }

// ---- helpers ----
__device__ __forceinline__ void gload_lds16(const bf16* g, bf16* l) {
    __builtin_amdgcn_global_load_lds(
        (const __attribute__((address_space(1))) unsigned int*)g,
        (__attribute__((address_space(3))) unsigned int*)l, 16, 0, 0);
}

__device__ __forceinline__ float wred_sum(float v) {
#pragma unroll
    for (int o = 32; o > 0; o >>= 1) v += __shfl_xor(v, o, 64);
    return v;
}

__device__ __forceinline__ float gelu_f(float x) {
    return 0.5f * x * (1.0f + erff(x * 0.70710678118654752440f));
}

// ---- xhat: LN-normalize (x + frame_embs[t]) once, no affine, bf16 out ----
__global__ __launch_bounds__(256) void xhat_k(const float* __restrict__ x,
                                              const float* __restrict__ fe,
                                              bf16* __restrict__ xhat) {
    __shared__ float red[8];
    int row = blockIdx.x;                // bt*FV + fv
    int t = (row >> 10) & 7;
    const float* xr = x + (size_t)row * D_;
    const float* fr_ = fe + (size_t)t * D_;
    int tid = threadIdx.x, c = tid * 4;
    float4 v = *(const float4*)(xr + c);
    float4 f = *(const float4*)(fr_ + c);
    v.x += f.x; v.y += f.y; v.z += f.z; v.w += f.w;
    float s = v.x + v.y + v.z + v.w;
    float ss = v.x * v.x + v.y * v.y + v.z * v.z + v.w * v.w;
    s = wred_sum(s); ss = wred_sum(ss);
    if ((tid & 63) == 0) { red[tid >> 6] = s; red[4 + (tid >> 6)] = ss; }
    __syncthreads();
    s = red[0] + red[1] + red[2] + red[3];
    ss = red[4] + red[5] + red[6] + red[7];
    float mean = s * (1.0f / D_);
    float rstd = rsqrtf(ss * (1.0f / D_) - mean * mean + 1e-5f);
    bf16x4 o;
    o[0] = (bf16)((v.x - mean) * rstd);
    o[1] = (bf16)((v.y - mean) * rstd);
    o[2] = (bf16)((v.z - mean) * rstd);
    o[3] = (bf16)((v.w - mean) * rstd);
    *(bf16x4*)(xhat + (size_t)row * D_ + c) = o;
}

// ---- lat init ----
__global__ __launch_bounds__(256) void latinit_k(const float* __restrict__ latents,
                                                 float* __restrict__ lat) {
    int row = blockIdx.x;
    int i = row & 63;
    int c = threadIdx.x * 4;
    float4 v = *(const float4*)(latents + (size_t)i * D_ + c);
    *(float4*)(lat + (size_t)row * D_ + c) = v;
}

// ---- row LayerNorm with affine: fp32 in, bf16 out ----
template<int OUTF>
__global__ __launch_bounds__(256) void ln_k(const float* __restrict__ in,
                                            const float* __restrict__ g,
                                            const float* __restrict__ b,
                                            void* __restrict__ out) {
    __shared__ float red[8];
    int row = blockIdx.x;
    const float* x = in + (size_t)row * D_;
    int tid = threadIdx.x, c = tid * 4;
    float4 v = *(const float4*)(x + c);
    float s = v.x + v.y + v.z + v.w;
    float ss = v.x * v.x + v.y * v.y + v.z * v.z + v.w * v.w;
    s = wred_sum(s); ss = wred_sum(ss);
    if ((tid & 63) == 0) { red[tid >> 6] = s; red[4 + (tid >> 6)] = ss; }
    __syncthreads();
    s = red[0] + red[1] + red[2] + red[3];
    ss = red[4] + red[5] + red[6] + red[7];
    float mean = s * (1.0f / D_);
    float rstd = rsqrtf(ss * (1.0f / D_) - mean * mean + 1e-5f);
    float4 gv = *(const float4*)(g + c);
    float4 bv = *(const float4*)(b + c);
    float o0 = (v.x - mean) * rstd * gv.x + bv.x;
    float o1 = (v.y - mean) * rstd * gv.y + bv.y;
    float o2 = (v.z - mean) * rstd * gv.z + bv.z;
    float o3 = (v.w - mean) * rstd * gv.w + bv.w;
    if (OUTF) {
        *(float4*)((float*)out + (size_t)row * D_ + c) = make_float4(o0, o1, o2, o3);
    } else {
        bf16x4 o; o[0] = (bf16)o0; o[1] = (bf16)o1; o[2] = (bf16)o2; o[3] = (bf16)o3;
        *(bf16x4*)((bf16*)out + (size_t)row * D_ + c) = o;
    }
}

// ---- accln: lat += sum of NP partials; LN(lat) -> out ----
template<int NP, int OUTF>
__global__ __launch_bounds__(256) void accln_k(float* __restrict__ lat,
                                               const float* __restrict__ p, long long s,
                                               const float* __restrict__ g,
                                               const float* __restrict__ b,
                                               void* __restrict__ out) {
    __shared__ float red[8];
    int row = blockIdx.x;
    int tid = threadIdx.x, c = tid * 4;
    float* lr = lat + (size_t)row * D_;
    float4 a = *(const float4*)(lr + c);
#pragma unroll
    for (int w = 0; w < NP; w++) {
        float4 x = *(const float4*)(p + (size_t)w * s + (size_t)row * D_ + c);
        a.x += x.x; a.y += x.y; a.z += x.z; a.w += x.w;
    }
    if (!OUTF) *(float4*)(lr + c) = a;
    float sm = a.x + a.y + a.z + a.w;
    float ss = a.x * a.x + a.y * a.y + a.z * a.z + a.w * a.w;
    sm = wred_sum(sm); ss = wred_sum(ss);
    if ((tid & 63) == 0) { red[tid >> 6] = sm; red[4 + (tid >> 6)] = ss; }
    __syncthreads();
    sm = red[0] + red[1] + red[2] + red[3];
    ss = red[4] + red[5] + red[6] + red[7];
    float mean = sm * (1.0f / D_);
    float rstd = rsqrtf(ss * (1.0f / D_) - mean * mean + 1e-5f);
    float4 gv = *(const float4*)(g + c);
    float4 bv = *(const float4*)(b + c);
    float o0 = (a.x - mean) * rstd * gv.x + bv.x;
    float o1 = (a.y - mean) * rstd * gv.y + bv.y;
    float o2 = (a.z - mean) * rstd * gv.z + bv.z;
    float o3 = (a.w - mean) * rstd * gv.w + bv.w;
    if (OUTF) {
        *(float4*)((float*)out + (size_t)row * D_ + c) = make_float4(o0, o1, o2, o3);
    } else {
        bf16x4 o; o[0] = (bf16)o0; o[1] = (bf16)o1; o[2] = (bf16)o2; o[3] = (bf16)o3;
        *(bf16x4*)((bf16*)out + (size_t)row * D_ + c) = o;
    }
}

// ---- fused weight prep, ALL LAYERS, 64x64 tiles ----
__device__ __forceinline__ void wt_tile64(const float* __restrict__ in, int R, int C,
                                          bf16* __restrict__ out, int bx, int by,
                                          const float* __restrict__ sc,
                                          const float* __restrict__ bm,
                                          float* __restrict__ bkv) {
    __shared__ float t[64][65];
    int c0 = bx * 64, r0 = by * 64;
    int tx = threadIdx.x & 63, ty = threadIdx.x >> 6;   // ty 0..3
#pragma unroll
    for (int i = 0; i < 16; i++)
        t[ty + i * 4][tx] = in[(size_t)(r0 + ty + i * 4) * C + c0 + tx];
    __syncthreads();
    float scale = sc ? sc[r0 + tx] : 1.0f;
#pragma unroll
    for (int i = 0; i < 16; i++)
        out[(size_t)(c0 + ty + i * 4) * R + r0 + tx] = (bf16)(t[tx][ty + i * 4] * scale);
    if (bm && ty == 0) {
        float s = 0.0f;
#pragma unroll
        for (int r = 0; r < 64; r++) s += bm[r0 + r] * t[r][tx];
        atomicAdd(&bkv[c0 + tx], s);
    }
}

// per-layer tiles: Wq 128 | BcatKV 256 | WkvTg 256 | Wo 128 | W1 1024 | W2 1024 = 2816
__global__ __launch_bounds__(256) void wprep_all(const float* __restrict__ Wq,
                                                 const float* __restrict__ Wkv,
                                                 const float* __restrict__ Wo,
                                                 const float* __restrict__ W1,
                                                 const float* __restrict__ W2,
                                                 const float* __restrict__ g_media,
                                                 const float* __restrict__ b_media,
                                                 float* __restrict__ bkv6,
                                                 bf16* __restrict__ Bcat6,
                                                 bf16* __restrict__ WkvTg6,
                                                 bf16* __restrict__ WoT6,
                                                 bf16* __restrict__ W1T6,
                                                 bf16* __restrict__ W2T6) {
    int l = blockIdx.x / 2816;
    int id = blockIdx.x - l * 2816;
    const float* wq  = Wq + (size_t)l * D_ * INNER_;
    const float* wkv = Wkv + (size_t)l * D_ * 2 * INNER_;
    const float* wo  = Wo + (size_t)l * INNER_ * D_;
    const float* w1  = W1 + (size_t)l * D_ * FF_;
    const float* w2  = W2 + (size_t)l * FF_ * D_;
    bf16* BcatQ  = Bcat6 + (size_t)l * 1536 * D_;
    bf16* BcatKV = BcatQ + (size_t)512 * D_;
    bf16* WkvTg  = WkvTg6 + (size_t)l * D_ * D_;
    bf16* WoT    = WoT6 + (size_t)l * D_ * INNER_;
    bf16* W1T    = W1T6 + (size_t)l * FF_ * D_;
    bf16* W2T    = W2T6 + (size_t)l * D_ * FF_;
    const float* gm = g_media + (size_t)l * D_;
    const float* bm = b_media + (size_t)l * D_;
    float* bkv = bkv6 + (size_t)l * 1024;
    if (id < 128)            wt_tile64(wq, D_, INNER_, BcatQ, id & 7, id >> 3, nullptr, nullptr, nullptr);
    else if (id < 384)   { int i = id - 128;  wt_tile64(wkv, D_, 2 * INNER_, BcatKV, i & 15, i >> 4, nullptr, nullptr, nullptr); }
    else if (id < 640)   { int i = id - 384;  wt_tile64(wkv, D_, 2 * INNER_, WkvTg, i & 15, i >> 4, gm, bm, bkv); }
    else if (id < 768)   { int i = id - 640;  wt_tile64(wo, INNER_, D_, WoT, i & 15, i >> 4, nullptr, nullptr, nullptr); }
    else if (id < 1792)  { int i = id - 768;  wt_tile64(w1, D_, FF_, W1T, i & 63, i >> 6, nullptr, nullptr, nullptr); }
    else                 { int i = id - 1792; wt_tile64(w2, FF_, D_, W2T, i & 15, i >> 4, nullptr, nullptr, nullptr); }
}

// ======== 128x256 pipelined-frag 4-phase NT GEMM (48KB LDS -> 3 blocks/CU) ========
// MODE 0: KV epilogue (+bias; cb<512 -> KVb ld512 KV-rows; cb>=512 -> vt transposed)
// MODE 3: bf16 gelu out.  MODE 4: fp32 split-K partial (czs stride).
template<int MODE>
__global__ __launch_bounds__(512, 1) void gemm_ff(const bf16* __restrict__ Ag, int lda,
                                                  const bf16* __restrict__ Bg, int ldb,
                                                  void* __restrict__ C, int ldc,
                                                  int K, long long czs,
                                                  const float* __restrict__ bias,
                                                  void* __restrict__ C2) {
    __shared__ bf16 lds[2][24576];   // [buf][A 0..8191 | Blo 8192 | Bhi 16384]
    const int tid = threadIdx.x;
    const int w = tid >> 6, lane = tid & 63;
    const int wm = w >> 2, wn = w & 3;
    const size_t m0 = (size_t)blockIdx.x * 128;
    const size_t n0 = (size_t)blockIdx.y * 256;
    const int klen = K / gridDim.z;
    const int koff = blockIdx.z * klen;
    const int nt = klen >> 6;

    const int p0 = (w * 2) * 64 + lane, p1 = p0 + 64;
    const int sr0 = p0 >> 3, sk0 = ((p0 & 7) ^ (sr0 & 7)) * 8;
    const int sr1 = p1 >> 3, sk1 = ((p1 & 7) ^ (sr1 & 7)) * 8;
    const int scw0 = (w * 2) * 512, scw1 = scw0 + 512;

    auto STAGE = [&](const bf16* g, int ld, size_t row0, int k0, bf16* bufb, int rb) {
        gload_lds16(g + (row0 + sr0) * (size_t)ld + k0 + sk0, bufb + rb + scw0);
        gload_lds16(g + (row0 + sr1) * (size_t)ld + k0 + sk1, bufb + rb + scw1);
    };

    const int fr = lane & 15;
    const int pK0 = (((lane >> 4)) ^ (fr & 7)) * 8;
    const int pK1 = ((4 + (lane >> 4)) ^ (fr & 7)) * 8;
    const size_t aoff = (size_t)(wm * 64 + fr) * 64;
    const size_t boff = 8192 + (size_t)(wn * 64 + fr) * 64;

    f32x4 acc[4][4];
#pragma unroll
    for (int i = 0; i < 4; i++)
#pragma unroll
        for (int j = 0; j < 4; j++)
#pragma unroll
            for (int r = 0; r < 4; r++) acc[i][j][r] = 0.0f;

    bf16x8 aX[2], aY[2], bA[4][2], bB[4][2];

    auto LDA1 = [&](const bf16* lb, int i0, bf16x8 (&d)[2]) {
        d[0] = *(const bf16x8*)(lb + aoff + (size_t)i0 * 1024 + pK0);
        d[1] = *(const bf16x8*)(lb + aoff + (size_t)i0 * 1024 + pK1);
    };
    auto LDB8 = [&](const bf16* lb, bf16x8 (&bb)[4][2]) {
#pragma unroll
        for (int j = 0; j < 4; j++) {
            bb[j][0] = *(const bf16x8*)(lb + boff + j * 1024 + pK0);
            bb[j][1] = *(const bf16x8*)(lb + boff + j * 1024 + pK1);
        }
    };
    auto MM1 = [&](int i0, bf16x8 (&a)[2], bf16x8 (&bb)[4][2]) {
        __builtin_amdgcn_s_setprio(1);
#pragma unroll
        for (int j = 0; j < 4; j++) {
            acc[i0][j] = __builtin_amdgcn_mfma_f32_16x16x32_bf16(a[0], bb[j][0], acc[i0][j], 0, 0, 0);
            acc[i0][j] = __builtin_amdgcn_mfma_f32_16x16x32_bf16(a[1], bb[j][1], acc[i0][j], 0, 0, 0);
        }
        __builtin_amdgcn_s_setprio(0);
    };

    // prologue: tile0 {A,Blo,Bhi} + tile1 {Blo,Bhi} = 10 loads
    STAGE(Ag, lda, m0,       koff,      lds[0], 0);
    STAGE(Bg, ldb, n0,       koff,      lds[0], 8192);
    STAGE(Bg, ldb, n0 + 128, koff,      lds[0], 16384);
    STAGE(Bg, ldb, n0,       koff + 64, lds[1], 8192);
    STAGE(Bg, ldb, n0 + 128, koff + 64, lds[1], 16384);
    asm volatile("s_waitcnt vmcnt(4)");   // tile0 landed
    BARRIER();
    LDB8(lds[0], bA);
    LDA1(lds[0], 0, aX);

    auto tile4 = [&](const bf16* lb, bf16* lbn, bf16x8 (&BU)[4][2], bf16x8 (&BL)[4][2], int t) {
        bf16* lbw = (bf16*)lb;
        LDA1(lb, 1, aY);
        if (t + 1 < nt) STAGE(Ag, lda, m0, koff + ((t + 1) << 6), lbn, 0);
        MM1(0, aX, BU);
        ENDPH();
        LDA1(lb, 2, aX);
        if (t + 2 < nt) STAGE(Bg, ldb, n0, koff + ((t + 2) << 6), lbw, 8192);
        MM1(1, aY, BU);
        ENDPH();
        LDA1(lb, 3, aY);
        if (t + 2 < nt) STAGE(Bg, ldb, n0 + 128, koff + ((t + 2) << 6), lbw, 16384);
        MM1(2, aX, BU);
        __builtin_amdgcn_sched_barrier(0);
        asm volatile("s_waitcnt lgkmcnt(0)");
        __builtin_amdgcn_sched_barrier(0);
        if (t < nt - 2)       { asm volatile("s_waitcnt vmcnt(4)"); }   // A(t+1) landed
        else if (t == nt - 2) { asm volatile("s_waitcnt vmcnt(0)"); }
        BARRIER();
        if (t + 1 < nt) { LDB8(lbn, BL); LDA1(lbn, 0, aX); }
        MM1(3, aY, BU);
        ENDPH();
    };

    for (int t = 0; t < nt; t += 2) {
        tile4(lds[0], lds[1], bA, bB, t);
        tile4(lds[1], lds[0], bB, bA, t + 1);
    }

    const int fq = (lane >> 4) * 4;
#pragma unroll
    for (int i = 0; i < 4; i++)
#pragma unroll
        for (int j = 0; j < 4; j++) {
            size_t cb = n0 + wn * 64 + j * 16 + fr;
            size_t mb = m0 + wm * 64 + i * 16 + fq;
            if (MODE == 0) {
                float bv = bias[cb];
                if (cb < 512) {
#pragma unroll
                    for (int r = 0; r < 4; r++) {
                        size_t m = mb + r;
                        size_t rb = m + ((m >> 10) << 6);
                        ((bf16*)C)[rb * 512 + cb] = (bf16)(acc[i][j][r] + bv);
                    }
                } else {
                    int hh = ((int)cb - 512) >> 6, dh = ((int)cb - 512) & 63;
                    size_t bt = mb >> 10, jl = mb & 1023;
                    bf16x4 v4;
#pragma unroll
                    for (int r = 0; r < 4; r++) v4[r] = (bf16)(acc[i][j][r] + bv);
                    *(bf16x4*)((bf16*)C2 + ((bt * 8 + hh) * 64 + dh) * (size_t)NKV_ + jl) = v4;
                }
            } else {
#pragma unroll
                for (int r = 0; r < 4; r++) {
                    float v = acc[i][j][r];
                    if (MODE == 4) {
                        ((float*)C + blockIdx.z * czs)[(mb + r) * (size_t)ldc + cb] = v;
                    } else {
                        ((bf16*)C)[(mb + r) * (size_t)ldc + cb] = (bf16)gelu_f(v);
                    }
                }
            }
        }
}

// ---- 128x128 NT GEMM (swizzled LDS) ----
template<int MODE, int CMAP>
__global__ __launch_bounds__(256) void gemm128(const bf16* __restrict__ A, int lda,
                                               const bf16* __restrict__ Bw, int ldb,
                                               void* __restrict__ C, int ldc,
                                               int K, float scale,
                                               long long czs, void* __restrict__ C2,
                                               void* __restrict__ C3) {
    __shared__ bf16 As[128 * 32];
    __shared__ bf16 Bs[128 * 32];
    const int tid = threadIdx.x;
    const int wave = tid >> 6;
    const int lane = tid & 63;
    const size_t m0 = (size_t)blockIdx.x * 128;
    const size_t n0 = (size_t)blockIdx.y * 128;
    const int wm = (wave >> 1) * 64;
    const int wn = (wave & 1) * 64;

    const int klen = K / gridDim.z;
    const int koff = blockIdx.z * klen;

    const int r0 = tid >> 2;
    const int c0 = ((tid & 3) ^ ((tid >> 3) & 3)) * 8;
    const bf16* ga0 = A + (m0 + r0) * lda + c0 + koff;
    const bf16* ga1 = A + (m0 + r0 + 64) * lda + c0 + koff;
    const bf16* gb0 = Bw + (n0 + r0) * ldb + c0 + koff;
    const bf16* gb1 = Bw + (n0 + r0 + 64) * ldb + c0 + koff;
    bf16* la0 = As + wave * 512;
    bf16* la1 = As + 2048 + wave * 512;
    bf16* lb0 = Bs + wave * 512;
    bf16* lb1 = Bs + 2048 + wave * 512;

    f32x4 acc[4][4];
#pragma unroll
    for (int i = 0; i < 4; i++)
#pragma unroll
        for (int j = 0; j < 4; j++)
#pragma unroll
            for (int r = 0; r < 4; r++) acc[i][j][r] = 0.0f;

    const int fr = lane & 15;
    const int q = lane >> 4;
    const int sw = (q ^ ((fr >> 1) & 3)) * 8;

    for (int kt = 0; kt < klen; kt += 32) {
        gload_lds16(ga0 + kt, la0);
        gload_lds16(ga1 + kt, la1);
        gload_lds16(gb0 + kt, lb0);
        gload_lds16(gb1 + kt, lb1);
        __syncthreads();
        bf16x8 af[4], bfv[4];
#pragma unroll
        for (int i = 0; i < 4; i++) {
            af[i]  = *(const bf16x8*)(As + (wm + i * 16 + fr) * 32 + sw);
            bfv[i] = *(const bf16x8*)(Bs + (wn + i * 16 + fr) * 32 + sw);
        }
#pragma unroll
        for (int i = 0; i < 4; i++)
#pragma unroll
            for (int j = 0; j < 4; j++)
                acc[i][j] = __builtin_amdgcn_mfma_f32_16x16x32_bf16(af[i], bfv[j], acc[i][j], 0, 0, 0);
        __syncthreads();
    }

    const int fq = (lane >> 4) * 4;
#pragma unroll
    for (int i = 0; i < 4; i++)
#pragma unroll
        for (int j = 0; j < 4; j++) {
            size_t cb = n0 + wn + j * 16 + fr;
            size_t mb = m0 + wm + i * 16 + fq;
            if (CMAP == 3) {
                if (cb < 512) {
#pragma unroll
                    for (int r = 0; r < 4; r++)
                        ((bf16*)C)[(mb + r) * 512 + cb] = (bf16)(acc[i][j][r] * scale);
                } else if (cb < 1024) {
#pragma unroll
                    for (int r = 0; r < 4; r++) {
                        size_t m = mb + r;
                        size_t rb = (m >> 6) * (size_t)NKV_ + 1024 + (m & 63);
                        ((bf16*)C2)[rb * 512 + (cb - 512)] = (bf16)acc[i][j][r];
                    }
                } else {
                    int hh = ((int)cb - 1024) >> 6, dh = ((int)cb - 1024) & 63;
                    size_t bt = mb >> 6, jl = 1024 + (mb & 63);
                    bf16x4 v4;
#pragma unroll
                    for (int r = 0; r < 4; r++) v4[r] = (bf16)acc[i][j][r];
                    *(bf16x4*)((bf16*)C3 + ((bt * 8 + hh) * 64 + dh) * (size_t)NKV_ + jl) = v4;
                }
            } else {
#pragma unroll
                for (int r = 0; r < 4; r++) {
                    float v = acc[i][j][r];
                    if (MODE == 4) {
                        ((float*)C + blockIdx.z * czs)[(mb + r) * ldc + cb] = v;
                    } else {
                        ((bf16*)C)[(mb + r) * ldc + cb] = (bf16)v;
                    }
                }
            }
        }
}

// ======== fused attention: one block per z + defer-max (THR=8) ========
__global__ __launch_bounds__(256, 2) void attn_k(const bf16* __restrict__ qb,
                                                 const bf16* __restrict__ KVb,
                                                 const bf16* __restrict__ vt,
                                                 bf16* __restrict__ ob) {
    __shared__ float comb[4][64 * 66];
    __shared__ float sc[4][64];
    __shared__ float mw[4][64], lw[4][64];
    const int z = blockIdx.x, bt = z >> 3, h = z & 7;
    const int tid = threadIdx.x, w = tid >> 6, lane = tid & 63;
    const int fr = lane & 15, g = lane >> 4;
    const bf16* Qz = qb + (size_t)(bt * 64) * INNER_ + h * DH_;
    const bf16* Kz = KVb + (size_t)bt * NKV_ * 512 + h * DH_;   // K rows, ld 512
    const bf16* Vz = vt + (size_t)z * (DH_ * NKV_);
    bf16* Pw = (bf16*)(&comb[w][0]);

    bf16x8 qf[4][2];
#pragma unroll
    for (int nj = 0; nj < 4; nj++)
#pragma unroll
        for (int ks = 0; ks < 2; ks++)
            qf[nj][ks] = *(const bf16x8*)(Qz + (size_t)(fr + 16 * nj) * INNER_ + g * 8 + ks * 32);

    f32x4 acc_o[4][4];
#pragma unroll
    for (int i = 0; i < 4; i++)
#pragma unroll
        for (int j = 0; j < 4; j++)
#pragma unroll
            for (int r = 0; r < 4; r++) acc_o[i][j][r] = 0.0f;
    float m_reg[4] = {-INFINITY, -INFINITY, -INFINITY, -INFINITY};
    float l_reg[4] = {0.0f, 0.0f, 0.0f, 0.0f};

    const int nch = (w == 0) ? 5 : 4;
    for (int ci = 0; ci < nch; ci++) {
        const int kc0 = (w + ci * 4) * 64;
        f32x4 s[4][4];
#pragma unroll
        for (int i = 0; i < 4; i++)
#pragma unroll
            for (int j = 0; j < 4; j++)
#pragma unroll
                for (int r = 0; r < 4; r++) s[i][j][r] = 0.0f;
#pragma unroll
        for (int ks = 0; ks < 2; ks++) {
            bf16x8 kf[4];
#pragma unroll
            for (int mi = 0; mi < 4; mi++)
                kf[mi] = *(const bf16x8*)(Kz + (size_t)(kc0 + fr + 16 * mi) * 512 + g * 8 + ks * 32);
#pragma unroll
            for (int mi = 0; mi < 4; mi++)
#pragma unroll
                for (int nj = 0; nj < 4; nj++)
                    s[mi][nj] = __builtin_amdgcn_mfma_f32_16x16x32_bf16(kf[mi], qf[nj][ks], s[mi][nj], 0, 0, 0);
        }
        float pmax[4];
#pragma unroll
        for (int nj = 0; nj < 4; nj++) {
            float mx = s[0][nj][0];
#pragma unroll
            for (int mi = 0; mi < 4; mi++)
#pragma unroll
                for (int r = 0; r < 4; r++) mx = fmaxf(mx, s[mi][nj][r]);
            mx = fmaxf(mx, __shfl_xor(mx, 16, 64));
            mx = fmaxf(mx, __shfl_xor(mx, 32, 64));
            pmax[nj] = mx;
        }
        // defer-max (T13, THR=8): rescale only when growth exceeds 8; P <= e^8
        bool big = (pmax[0] > m_reg[0] + 8.0f) || (pmax[1] > m_reg[1] + 8.0f) ||
                   (pmax[2] > m_reg[2] + 8.0f) || (pmax[3] > m_reg[3] + 8.0f);
        if (__any(big ? 1 : 0)) {
            float so[4];
#pragma unroll
            for (int nj = 0; nj < 4; nj++) {
                float mn = fmaxf(m_reg[nj], pmax[nj]);
                so[nj] = __expf(m_reg[nj] - mn);
                m_reg[nj] = mn;
                l_reg[nj] *= so[nj];
            }
            if (g == 0) {
#pragma unroll
                for (int nj = 0; nj < 4; nj++) sc[w][fr + 16 * nj] = so[nj];
            }
            asm volatile("s_waitcnt lgkmcnt(0)" ::: "memory");
#pragma unroll
            for (int mi = 0; mi < 4; mi++)
#pragma unroll
                for (int r = 0; r < 4; r++) {
                    float sq = sc[w][16 * mi + 4 * g + r];
#pragma unroll
                    for (int jd = 0; jd < 4; jd++) acc_o[mi][jd][r] *= sq;
                }
        }
        float psum[4] = {0.0f, 0.0f, 0.0f, 0.0f};
#pragma unroll
        for (int mi = 0; mi < 4; mi++)
#pragma unroll
            for (int nj = 0; nj < 4; nj++) {
                bf16x4 pb4;
#pragma unroll
                for (int r = 0; r < 4; r++) {
                    float pv = __expf(s[mi][nj][r] - m_reg[nj]);
                    psum[nj] += pv;
                    pb4[r] = (bf16)pv;
                }
                *(bf16x4*)(Pw + (size_t)(fr + 16 * nj) * 72 + 16 * mi + 4 * g) = pb4;
            }
#pragma unroll
        for (int nj = 0; nj < 4; nj++) {
            float ps = psum[nj];
            ps += __shfl_xor(ps, 16, 64);
            ps += __shfl_xor(ps, 32, 64);
            l_reg[nj] += ps;
        }
        asm volatile("s_waitcnt lgkmcnt(0)" ::: "memory");
#pragma unroll
        for (int ks = 0; ks < 2; ks++) {
            bf16x8 af[4], vf[4];
#pragma unroll
            for (int mi = 0; mi < 4; mi++)
                af[mi] = *(const bf16x8*)(Pw + (size_t)(fr + 16 * mi) * 72 + g * 8 + ks * 32);
#pragma unroll
            for (int jd = 0; jd < 4; jd++)
                vf[jd] = *(const bf16x8*)(Vz + (size_t)(fr + 16 * jd) * NKV_ + kc0 + g * 8 + ks * 32);
#pragma unroll
            for (int mi = 0; mi < 4; mi++)
#pragma unroll
                for (int jd = 0; jd < 4; jd++)
                    acc_o[mi][jd] = __builtin_amdgcn_mfma_f32_16x16x32_bf16(af[mi], vf[jd], acc_o[mi][jd], 0, 0, 0);
        }
    }

    if (g == 0) {
#pragma unroll
        for (int nj = 0; nj < 4; nj++) {
            mw[w][fr + 16 * nj] = m_reg[nj];
            lw[w][fr + 16 * nj] = l_reg[nj];
        }
    }
    asm volatile("s_waitcnt lgkmcnt(0)" ::: "memory");
#pragma unroll
    for (int mi = 0; mi < 4; mi++)
#pragma unroll
        for (int jd = 0; jd < 4; jd++)
#pragma unroll
            for (int r = 0; r < 4; r++)
                comb[w][(16 * mi + 4 * g + r) * 66 + fr + 16 * jd] = acc_o[mi][jd][r];
    __syncthreads();
    {
        int q = tid >> 2, d0 = (tid & 3) * 16;
        float M = fmaxf(fmaxf(mw[0][q], mw[1][q]), fmaxf(mw[2][q], mw[3][q]));
        float al[4], l = 0.0f;
#pragma unroll
        for (int ww = 0; ww < 4; ww++) { al[ww] = __expf(mw[ww][q] - M); l += al[ww] * lw[ww][q]; }
        float inv = 1.0f / l;
        bf16 outv[16];
#pragma unroll
        for (int dd = 0; dd < 16; dd++) {
            float o = 0.0f;
#pragma unroll
            for (int ww = 0; ww < 4; ww++) o += comb[ww][q * 66 + d0 + dd] * al[ww];
            outv[dd] = (bf16)(o * inv);
        }
        bf16* dst = ob + (size_t)(bt * 64 + q) * INNER_ + h * 64 + d0;
        *(bf16x8*)dst = *(bf16x8*)outv;
        *(bf16x8*)(dst + 8) = *(bf16x8*)(outv + 8);
    }
}

// ---- host side ----
extern "C" void kernel_launch(void* const* d_in, const int* in_sizes, int n_in,
                              void* d_out, int out_size, void* d_ws, size_t ws_size,
                              hipStream_t stream) {
    const float* x       = (const float*)d_in[0];
    const float* latents = (const float*)d_in[1];
    const float* fe      = (const float*)d_in[2];
    const float* g_media = (const float*)d_in[3];
    const float* b_media = (const float*)d_in[4];
    const float* g_lat   = (const float*)d_in[5];
    const float* b_lat   = (const float*)d_in[6];
    const float* Wq      = (const float*)d_in[7];
    const float* Wkv     = (const float*)d_in[8];
    const float* Wo      = (const float*)d_in[9];
    const float* g_ff    = (const float*)d_in[10];
    const float* b_ff    = (const float*)d_in[11];
    const float* W1      = (const float*)d_in[12];
    const float* W2      = (const float*)d_in[13];
    const float* g_out   = (const float*)d_in[14];
    const float* b_out   = (const float*)d_in[15];

    char* p = (char*)d_ws;
    auto alloc = [&](size_t bytes) { char* r = p; p += (bytes + 255) & ~(size_t)255; return r; };
    bf16*  xhat  = (bf16*)alloc((size_t)MROWS_ * D_ * 2);           // 67 MB
    float* lat   = (float*)alloc((size_t)2048 * D_ * 4);            // 8 MB
    bf16*  lnl   = (bf16*)alloc((size_t)2048 * D_ * 2);             // 4 MB
    bf16*  qb    = (bf16*)alloc((size_t)2048 * INNER_ * 2);         // 2 MB
    bf16*  KVb   = (bf16*)alloc((size_t)KVROWS_ * 512 * 2);         // 36 MB
    bf16*  vt    = (bf16*)alloc((size_t)ZB_ * DH_ * NKV_ * 2);      // 36 MB
    bf16*  ob    = (bf16*)alloc((size_t)2048 * INNER_ * 2);         // 2 MB
    bf16*  Bcat6 = (bf16*)alloc((size_t)L_ * 1536 * D_ * 2);        // 19 MB
    bf16*  WkvTg6= (bf16*)alloc((size_t)L_ * D_ * D_ * 2);          // 13 MB
    bf16*  WoT6  = (bf16*)alloc((size_t)L_ * D_ * INNER_ * 2);      // 6 MB
    bf16*  W1T6  = (bf16*)alloc((size_t)L_ * FF_ * D_ * 2);         // 50 MB
    bf16*  W2T6  = (bf16*)alloc((size_t)L_ * D_ * FF_ * 2);         // 50 MB
    float* bkv6  = (float*)alloc((size_t)L_ * 1024 * 4);
    float* ffp   = (float*)alloc((size_t)4 * 2048 * D_ * 4);        // 32 MB
    bf16*  ffh   = vt;           // alias: vt dead once attn done

    // setup (once per call)
    xhat_k<<<MROWS_, 256, 0, stream>>>(x, fe, xhat);
    latinit_k<<<2048, 256, 0, stream>>>(latents, lat);
    ln_k<0><<<2048, 256, 0, stream>>>(lat, g_lat, b_lat, lnl);   // layer-0 latent LN
    hipMemsetAsync(bkv6, 0, (size_t)L_ * 1024 * 4, stream);
    wprep_all<<<L_ * 2816, 256, 0, stream>>>(Wq, Wkv, Wo, W1, W2, g_media, b_media,
                                             bkv6, Bcat6, WkvTg6, WoT6, W1T6, W2T6);

    const long long PS = (long long)2048 * D_;

    for (int l = 0; l < L_; l++) {
        const float* gf = g_ff + (size_t)l * D_;
        const float* bf_ = b_ff + (size_t)l * D_;
        bf16* Bcat  = Bcat6 + (size_t)l * 1536 * D_;
        bf16* WkvTg = WkvTg6 + (size_t)l * D_ * D_;
        bf16* WoT   = WoT6 + (size_t)l * D_ * INNER_;
        bf16* W1T   = W1T6 + (size_t)l * FF_ * D_;
        bf16* W2T   = W2T6 + (size_t)l * D_ * FF_;
        float* bkv  = bkv6 + (size_t)l * 1024;

        // KV x-part: K -> KVb, V -> vt (transposed), +bkv   [128x256, 3 blocks/CU]
        gemm_ff<0><<<dim3(256, 4), 512, 0, stream>>>(
            xhat, D_, WkvTg, D_, KVb, 0, 1024, 0, bkv, vt);
        // merged: q = (lnl@WqT)*scale; KV lat rows: K -> KVb, V -> vt
        gemm128<0, 3><<<dim3(16, 12), 256, 0, stream>>>(
            lnl, D_, Bcat, D_, qb, 0, D_, 0.125f, 0, KVb, vt);

        // fused attention -> ob
        attn_k<<<ZB_, 256, 0, stream>>>(qb, KVb, vt, ob);

        // Wo split-K 2 -> fp32 partials
        gemm128<4, 0><<<dim3(16, 8, 2), 256, 0, stream>>>(
            ob, INNER_, WoT, INNER_, ffp, D_, INNER_, 1.0f, PS, nullptr, nullptr);
        // lat += partials; lnl = LN(lat; gf,bf)
        accln_k<2, 0><<<2048, 256, 0, stream>>>(lat, ffp, PS, gf, bf_, lnl);

        // FF1: ffh = gelu(lnl @ W1T)   [pipelined 128x256]
        gemm_ff<3><<<dim3(16, 16), 512, 0, stream>>>(
            lnl, D_, W1T, D_, ffh, FF_, 1024, 0, nullptr, nullptr);
        // FF2 split-K 4 -> fp32 partials
        gemm_ff<4><<<dim3(16, 4, 4), 512, 0, stream>>>(
            ffh, FF_, W2T, FF_, ffp, D_, FF_, PS, nullptr, nullptr);
        // lat += partials; next-layer latent LN (or final LN -> d_out)
        if (l < L_ - 1) {
            accln_k<4, 0><<<2048, 256, 0, stream>>>(lat, ffp, PS,
                g_lat + (size_t)(l + 1) * D_, b_lat + (size_t)(l + 1) * D_, lnl);
        } else {
            accln_k<4, 1><<<2048, 256, 0, stream>>>(lat, ffp, PS, g_out, b_out, (float*)d_out);
        }
    }
}

// Round 13
// 1277.937 us; speedup vs baseline: 1.1153x; 1.1153x over previous
//
#include <hip/hip_runtime.h>
#include <math.h>

// ---- problem constants ----
#define D_      1024
#define DH_     64
#define H_      8
#define INNER_  512
#define L_      6
#define NL_     64
#define FF_     4096
#define B_      4
#define T_      8
#define FV_     1024          // F*V
#define BT_     32            // B*T
#define MROWS_  32768         // BT*FV
#define NKV_    1088          // FV + NL
#define KVROWS_ 34816         // BT*NKV
#define ZB_     256           // BT*H

typedef __bf16 bf16;
typedef __bf16 bf16x8 __attribute__((ext_vector_type(8)));
typedef __bf16 bf16x4 __attribute__((ext_vector_type(4)));
typedef float  f32x4  __attribute__((ext_vector_type(4)));

#define BARRIER() { asm volatile("" ::: "memory"); __builtin_amdgcn_s_barrier(); asm volatile("" ::: "memory"); }
// end-of-phase (FF pipelined schedule): pin ds_reads above, drain, barrier.
#define ENDPH() { __builtin_amdgcn_sched_barrier(0); asm volatile("s_waitcnt lgkmcnt(0)"); __builtin_amdgcn_sched_barrier(0); BARRIER(); }

// ---- helpers ----
__device__ __forceinline__ void gload_lds16(const bf16* g, bf16* l) {
    __builtin_amdgcn_global_load_lds(
        (const __attribute__((address_space(1))) unsigned int*)g,
        (__attribute__((address_space(3))) unsigned int*)l, 16, 0, 0);
}

__device__ __forceinline__ float wred_sum(float v) {
#pragma unroll
    for (int o = 32; o > 0; o >>= 1) v += __shfl_xor(v, o, 64);
    return v;
}

__device__ __forceinline__ float gelu_f(float x) {
    return 0.5f * x * (1.0f + erff(x * 0.70710678118654752440f));
}

// ---- xhat: LN-normalize (x + frame_embs[t]) once, no affine, bf16 out ----
__global__ __launch_bounds__(256) void xhat_k(const float* __restrict__ x,
                                              const float* __restrict__ fe,
                                              bf16* __restrict__ xhat) {
    __shared__ float red[8];
    int row = blockIdx.x;                // bt*FV + fv
    int t = (row >> 10) & 7;
    const float* xr = x + (size_t)row * D_;
    const float* fr_ = fe + (size_t)t * D_;
    int tid = threadIdx.x, c = tid * 4;
    float4 v = *(const float4*)(xr + c);
    float4 f = *(const float4*)(fr_ + c);
    v.x += f.x; v.y += f.y; v.z += f.z; v.w += f.w;
    float s = v.x + v.y + v.z + v.w;
    float ss = v.x * v.x + v.y * v.y + v.z * v.z + v.w * v.w;
    s = wred_sum(s); ss = wred_sum(ss);
    if ((tid & 63) == 0) { red[tid >> 6] = s; red[4 + (tid >> 6)] = ss; }
    __syncthreads();
    s = red[0] + red[1] + red[2] + red[3];
    ss = red[4] + red[5] + red[6] + red[7];
    float mean = s * (1.0f / D_);
    float rstd = rsqrtf(ss * (1.0f / D_) - mean * mean + 1e-5f);
    bf16x4 o;
    o[0] = (bf16)((v.x - mean) * rstd);
    o[1] = (bf16)((v.y - mean) * rstd);
    o[2] = (bf16)((v.z - mean) * rstd);
    o[3] = (bf16)((v.w - mean) * rstd);
    *(bf16x4*)(xhat + (size_t)row * D_ + c) = o;
}

// ---- lat init ----
__global__ __launch_bounds__(256) void latinit_k(const float* __restrict__ latents,
                                                 float* __restrict__ lat) {
    int row = blockIdx.x;
    int i = row & 63;
    int c = threadIdx.x * 4;
    float4 v = *(const float4*)(latents + (size_t)i * D_ + c);
    *(float4*)(lat + (size_t)row * D_ + c) = v;
}

// ---- row LayerNorm with affine: fp32 in, bf16 out ----
template<int OUTF>
__global__ __launch_bounds__(256) void ln_k(const float* __restrict__ in,
                                            const float* __restrict__ g,
                                            const float* __restrict__ b,
                                            void* __restrict__ out) {
    __shared__ float red[8];
    int row = blockIdx.x;
    const float* x = in + (size_t)row * D_;
    int tid = threadIdx.x, c = tid * 4;
    float4 v = *(const float4*)(x + c);
    float s = v.x + v.y + v.z + v.w;
    float ss = v.x * v.x + v.y * v.y + v.z * v.z + v.w * v.w;
    s = wred_sum(s); ss = wred_sum(ss);
    if ((tid & 63) == 0) { red[tid >> 6] = s; red[4 + (tid >> 6)] = ss; }
    __syncthreads();
    s = red[0] + red[1] + red[2] + red[3];
    ss = red[4] + red[5] + red[6] + red[7];
    float mean = s * (1.0f / D_);
    float rstd = rsqrtf(ss * (1.0f / D_) - mean * mean + 1e-5f);
    float4 gv = *(const float4*)(g + c);
    float4 bv = *(const float4*)(b + c);
    float o0 = (v.x - mean) * rstd * gv.x + bv.x;
    float o1 = (v.y - mean) * rstd * gv.y + bv.y;
    float o2 = (v.z - mean) * rstd * gv.z + bv.z;
    float o3 = (v.w - mean) * rstd * gv.w + bv.w;
    if (OUTF) {
        *(float4*)((float*)out + (size_t)row * D_ + c) = make_float4(o0, o1, o2, o3);
    } else {
        bf16x4 o; o[0] = (bf16)o0; o[1] = (bf16)o1; o[2] = (bf16)o2; o[3] = (bf16)o3;
        *(bf16x4*)((bf16*)out + (size_t)row * D_ + c) = o;
    }
}

// ---- accln: lat += sum of NP partials; LN(lat) -> out ----
template<int NP, int OUTF>
__global__ __launch_bounds__(256) void accln_k(float* __restrict__ lat,
                                               const float* __restrict__ p, long long s,
                                               const float* __restrict__ g,
                                               const float* __restrict__ b,
                                               void* __restrict__ out) {
    __shared__ float red[8];
    int row = blockIdx.x;
    int tid = threadIdx.x, c = tid * 4;
    float* lr = lat + (size_t)row * D_;
    float4 a = *(const float4*)(lr + c);
#pragma unroll
    for (int w = 0; w < NP; w++) {
        float4 x = *(const float4*)(p + (size_t)w * s + (size_t)row * D_ + c);
        a.x += x.x; a.y += x.y; a.z += x.z; a.w += x.w;
    }
    if (!OUTF) *(float4*)(lr + c) = a;
    float sm = a.x + a.y + a.z + a.w;
    float ss = a.x * a.x + a.y * a.y + a.z * a.z + a.w * a.w;
    sm = wred_sum(sm); ss = wred_sum(ss);
    if ((tid & 63) == 0) { red[tid >> 6] = sm; red[4 + (tid >> 6)] = ss; }
    __syncthreads();
    sm = red[0] + red[1] + red[2] + red[3];
    ss = red[4] + red[5] + red[6] + red[7];
    float mean = sm * (1.0f / D_);
    float rstd = rsqrtf(ss * (1.0f / D_) - mean * mean + 1e-5f);
    float4 gv = *(const float4*)(g + c);
    float4 bv = *(const float4*)(b + c);
    float o0 = (a.x - mean) * rstd * gv.x + bv.x;
    float o1 = (a.y - mean) * rstd * gv.y + bv.y;
    float o2 = (a.z - mean) * rstd * gv.z + bv.z;
    float o3 = (a.w - mean) * rstd * gv.w + bv.w;
    if (OUTF) {
        *(float4*)((float*)out + (size_t)row * D_ + c) = make_float4(o0, o1, o2, o3);
    } else {
        bf16x4 o; o[0] = (bf16)o0; o[1] = (bf16)o1; o[2] = (bf16)o2; o[3] = (bf16)o3;
        *(bf16x4*)((bf16*)out + (size_t)row * D_ + c) = o;
    }
}

// ---- fused weight prep (per layer) + bkv accumulation in WkvTg branch ----
__device__ __forceinline__ void wt_tile(const float* __restrict__ in, int R, int C,
                                        bf16* __restrict__ out, int bx, int by,
                                        const float* __restrict__ sc,
                                        const float* __restrict__ bm,
                                        float* __restrict__ bkv) {
    __shared__ float t[32][33];
    int c0 = bx * 32, r0 = by * 32;
    int tx = threadIdx.x & 31, ty = threadIdx.x >> 5;
#pragma unroll
    for (int i = 0; i < 4; i++)
        t[ty + i * 8][tx] = in[(size_t)(r0 + ty + i * 8) * C + c0 + tx];
    __syncthreads();
    float scale = sc ? sc[r0 + tx] : 1.0f;
#pragma unroll
    for (int i = 0; i < 4; i++)
        out[(size_t)(c0 + ty + i * 8) * R + r0 + tx] = (bf16)(t[tx][ty + i * 8] * scale);
    if (bm && ty == 0) {
        float s = 0.0f;
#pragma unroll
        for (int r = 0; r < 32; r++) s += bm[r0 + r] * t[r][tx];
        atomicAdd(&bkv[c0 + tx], s);
    }
}

__global__ __launch_bounds__(256) void wprep_k(const float* __restrict__ wq,
                                               const float* __restrict__ wkv,
                                               const float* __restrict__ wo,
                                               const float* __restrict__ w1,
                                               const float* __restrict__ w2,
                                               const float* __restrict__ gm,
                                               const float* __restrict__ bm,
                                               float* __restrict__ bkv,
                                               bf16* __restrict__ BcatQ,   // rows 0..511
                                               bf16* __restrict__ BcatKV,  // rows 512..1535
                                               bf16* __restrict__ WkvTg,
                                               bf16* __restrict__ WoT,
                                               bf16* __restrict__ W1T,
                                               bf16* __restrict__ W2T) {
    int id = blockIdx.x;
    if (id < 512)            wt_tile(wq, D_, INNER_, BcatQ, id & 15, id >> 4, nullptr, nullptr, nullptr);
    else if (id < 1536)  { int i = id - 512;  wt_tile(wkv, D_, 2 * INNER_, BcatKV, i & 31, i >> 5, nullptr, nullptr, nullptr); }
    else if (id < 2560)  { int i = id - 1536; wt_tile(wkv, D_, 2 * INNER_, WkvTg, i & 31, i >> 5, gm, bm, bkv); }
    else if (id < 3072)  { int i = id - 2560; wt_tile(wo, INNER_, D_, WoT, i & 31, i >> 5, nullptr, nullptr, nullptr); }
    else if (id < 7168)  { int i = id - 3072; wt_tile(w1, D_, FF_, W1T, i & 127, i >> 7, nullptr, nullptr, nullptr); }
    else                 { int i = id - 7168; wt_tile(w2, FF_, D_, W2T, i & 31, i >> 5, nullptr, nullptr, nullptr); }
}

// ======== KV GEMM: 256x256 8-phase pipelined NT (proven schedule) ========
__global__ __launch_bounds__(512, 1) void gemm_kv(const bf16* __restrict__ Ag,
                                                  const bf16* __restrict__ Bg,
                                                  bf16* __restrict__ KVb,
                                                  bf16* __restrict__ vt,
                                                  const float* __restrict__ bias) {
    __shared__ bf16 lds[2][32768];   // [buf][Alo 0 | Ahi 8192 | Blo 16384 | Bhi 24576]
    const int lda = D_, ldb = D_;
    const int tid = threadIdx.x;
    const int w = tid >> 6, lane = tid & 63;
    const int wm = w >> 2, wn = w & 3;
    const size_t m0 = (size_t)blockIdx.x * 256;
    const size_t n0 = (size_t)blockIdx.y * 256;
    const int nt = 16;   // K=1024, BK=64

    const int p0 = (w * 2) * 64 + lane, p1 = p0 + 64;
    const int sr0 = p0 >> 3, sk0 = ((p0 & 7) ^ (sr0 & 7)) * 8;
    const int sr1 = p1 >> 3, sk1 = ((p1 & 7) ^ (sr1 & 7)) * 8;
    const int scw0 = (w * 2) * 512, scw1 = scw0 + 512;

    auto STAGE = [&](const bf16* g, int ld, size_t row0, int k0, bf16* bufb, int rb) {
        gload_lds16(g + (row0 + sr0) * (size_t)ld + k0 + sk0, bufb + rb + scw0);
        gload_lds16(g + (row0 + sr1) * (size_t)ld + k0 + sk1, bufb + rb + scw1);
    };

    const int fr = lane & 15;
    const int pK0 = (((lane >> 4)) ^ (fr & 7)) * 8;
    const int pK1 = ((4 + (lane >> 4)) ^ (fr & 7)) * 8;
    const size_t aoff = (size_t)(wm * 128 + fr) * 64;
    const size_t boff = 16384 + (size_t)(wn * 64 + fr) * 64;

    f32x4 acc[8][4];
#pragma unroll
    for (int i = 0; i < 8; i++)
#pragma unroll
        for (int j = 0; j < 4; j++)
#pragma unroll
            for (int r = 0; r < 4; r++) acc[i][j][r] = 0.0f;

    STAGE(Bg, ldb, n0,       0, lds[0], 16384);
    STAGE(Bg, ldb, n0 + 128, 0, lds[0], 24576);
    STAGE(Ag, lda, m0,       0, lds[0], 0);
    STAGE(Ag, lda, m0 + 128, 0, lds[0], 8192);
    STAGE(Bg, ldb, n0,       64, lds[1], 16384);
    STAGE(Bg, ldb, n0 + 128, 64, lds[1], 24576);
    STAGE(Ag, lda, m0,       64, lds[1], 0);
    asm volatile("s_waitcnt vmcnt(6)");
    BARRIER();

    for (int t = 0; t < nt; ++t) {
        const bf16* lb = lds[t & 1];
        bf16* lbw = lds[t & 1];
        bf16* lbn = lds[(t + 1) & 1];
        const int kt1 = (t + 1) << 6, kt2 = (t + 2) << 6;
        bf16x8 bfr[4][2];

        {
#pragma unroll
            for (int j = 0; j < 4; j++) {
                bfr[j][0] = *(const bf16x8*)(lb + boff + j * 1024 + pK0);
                bfr[j][1] = *(const bf16x8*)(lb + boff + j * 1024 + pK1);
            }
            bf16x8 a00 = *(const bf16x8*)(lb + aoff + 0 * 1024 + pK0);
            bf16x8 a01 = *(const bf16x8*)(lb + aoff + 0 * 1024 + pK1);
            bf16x8 a10 = *(const bf16x8*)(lb + aoff + 1 * 1024 + pK0);
            bf16x8 a11 = *(const bf16x8*)(lb + aoff + 1 * 1024 + pK1);
            if (t + 1 < nt) STAGE(Ag, lda, m0 + 128, kt1, lbn, 8192);
            BARRIER();
            asm volatile("s_waitcnt lgkmcnt(0)");
            __builtin_amdgcn_s_setprio(1);
#pragma unroll
            for (int j = 0; j < 4; j++) {
                acc[0][j] = __builtin_amdgcn_mfma_f32_16x16x32_bf16(a00, bfr[j][0], acc[0][j], 0, 0, 0);
                acc[0][j] = __builtin_amdgcn_mfma_f32_16x16x32_bf16(a01, bfr[j][1], acc[0][j], 0, 0, 0);
                acc[1][j] = __builtin_amdgcn_mfma_f32_16x16x32_bf16(a10, bfr[j][0], acc[1][j], 0, 0, 0);
                acc[1][j] = __builtin_amdgcn_mfma_f32_16x16x32_bf16(a11, bfr[j][1], acc[1][j], 0, 0, 0);
            }
            __builtin_amdgcn_s_setprio(0);
            BARRIER();
        }
        {
            bf16x8 a00 = *(const bf16x8*)(lb + aoff + 2 * 1024 + pK0);
            bf16x8 a01 = *(const bf16x8*)(lb + aoff + 2 * 1024 + pK1);
            bf16x8 a10 = *(const bf16x8*)(lb + aoff + 3 * 1024 + pK0);
            bf16x8 a11 = *(const bf16x8*)(lb + aoff + 3 * 1024 + pK1);
            if (t + 2 < nt) STAGE(Bg, ldb, n0, kt2, lbw, 16384);
            BARRIER();
            asm volatile("s_waitcnt lgkmcnt(0)");
            __builtin_amdgcn_s_setprio(1);
#pragma unroll
            for (int j = 0; j < 4; j++) {
                acc[2][j] = __builtin_amdgcn_mfma_f32_16x16x32_bf16(a00, bfr[j][0], acc[2][j], 0, 0, 0);
                acc[2][j] = __builtin_amdgcn_mfma_f32_16x16x32_bf16(a01, bfr[j][1], acc[2][j], 0, 0, 0);
                acc[3][j] = __builtin_amdgcn_mfma_f32_16x16x32_bf16(a10, bfr[j][0], acc[3][j], 0, 0, 0);
                acc[3][j] = __builtin_amdgcn_mfma_f32_16x16x32_bf16(a11, bfr[j][1], acc[3][j], 0, 0, 0);
            }
            __builtin_amdgcn_s_setprio(0);
            BARRIER();
        }
        {
            bf16x8 a00 = *(const bf16x8*)(lb + aoff + 4 * 1024 + pK0);
            bf16x8 a01 = *(const bf16x8*)(lb + aoff + 4 * 1024 + pK1);
            bf16x8 a10 = *(const bf16x8*)(lb + aoff + 5 * 1024 + pK0);
            bf16x8 a11 = *(const bf16x8*)(lb + aoff + 5 * 1024 + pK1);
            if (t + 2 < nt) STAGE(Bg, ldb, n0 + 128, kt2, lbw, 24576);
            BARRIER();
            asm volatile("s_waitcnt lgkmcnt(0)");
            __builtin_amdgcn_s_setprio(1);
#pragma unroll
            for (int j = 0; j < 4; j++) {
                acc[4][j] = __builtin_amdgcn_mfma_f32_16x16x32_bf16(a00, bfr[j][0], acc[4][j], 0, 0, 0);
                acc[4][j] = __builtin_amdgcn_mfma_f32_16x16x32_bf16(a01, bfr[j][1], acc[4][j], 0, 0, 0);
                acc[5][j] = __builtin_amdgcn_mfma_f32_16x16x32_bf16(a10, bfr[j][0], acc[5][j], 0, 0, 0);
                acc[5][j] = __builtin_amdgcn_mfma_f32_16x16x32_bf16(a11, bfr[j][1], acc[5][j], 0, 0, 0);
            }
            __builtin_amdgcn_s_setprio(0);
            BARRIER();
        }
        {
            bf16x8 a00 = *(const bf16x8*)(lb + aoff + 6 * 1024 + pK0);
            bf16x8 a01 = *(const bf16x8*)(lb + aoff + 6 * 1024 + pK1);
            bf16x8 a10 = *(const bf16x8*)(lb + aoff + 7 * 1024 + pK0);
            bf16x8 a11 = *(const bf16x8*)(lb + aoff + 7 * 1024 + pK1);
            if (t + 2 < nt) STAGE(Ag, lda, m0, kt2, lbw, 0);
            BARRIER();
            asm volatile("s_waitcnt lgkmcnt(0)");
            __builtin_amdgcn_s_setprio(1);
#pragma unroll
            for (int j = 0; j < 4; j++) {
                acc[6][j] = __builtin_amdgcn_mfma_f32_16x16x32_bf16(a00, bfr[j][0], acc[6][j], 0, 0, 0);
                acc[6][j] = __builtin_amdgcn_mfma_f32_16x16x32_bf16(a01, bfr[j][1], acc[6][j], 0, 0, 0);
                acc[7][j] = __builtin_amdgcn_mfma_f32_16x16x32_bf16(a10, bfr[j][0], acc[7][j], 0, 0, 0);
                acc[7][j] = __builtin_amdgcn_mfma_f32_16x16x32_bf16(a11, bfr[j][1], acc[7][j], 0, 0, 0);
            }
            __builtin_amdgcn_s_setprio(0);
            if (t < nt - 2)       { asm volatile("s_waitcnt vmcnt(6)"); }
            else if (t == nt - 2) { asm volatile("s_waitcnt vmcnt(0)"); }
            BARRIER();
        }
    }

    // epilogue: K -> KVb (ld 512), V -> vt transposed
    const int fq = (lane >> 4) * 4;
#pragma unroll
    for (int i = 0; i < 8; i++)
#pragma unroll
        for (int j = 0; j < 4; j++) {
            size_t cb = n0 + wn * 64 + j * 16 + fr;
            float bv = bias[cb];
            size_t mb = m0 + wm * 128 + i * 16 + fq;
            if (cb < 512) {
#pragma unroll
                for (int r = 0; r < 4; r++) {
                    size_t m = mb + r;
                    size_t rb = m + ((m >> 10) << 6);
                    KVb[rb * 512 + cb] = (bf16)(acc[i][j][r] + bv);
                }
            } else {
                int hh = ((int)cb - 512) >> 6, dh = ((int)cb - 512) & 63;
                size_t bt = mb >> 10, jl = mb & 1023;
                bf16x4 v4;
#pragma unroll
                for (int r = 0; r < 4; r++) v4[r] = (bf16)(acc[i][j][r] + bv);
                *(bf16x4*)(vt + ((bt * 8 + hh) * 64 + dh) * (size_t)NKV_ + jl) = v4;
            }
        }
}

// ======== FF GEMM: 128x256, pipelined-frag 4-phase schedule ========
// MODE 3: bf16 gelu out. MODE 4: fp32 split-K partial (czs stride).
template<int MODE>
__global__ __launch_bounds__(512, 1) void gemm_ff(const bf16* __restrict__ Ag, int lda,
                                                  const bf16* __restrict__ Bg, int ldb,
                                                  void* __restrict__ C, int ldc,
                                                  int K, long long czs) {
    __shared__ bf16 lds[2][24576];   // [buf][A 0..8191 | Blo 8192 | Bhi 16384]
    const int tid = threadIdx.x;
    const int w = tid >> 6, lane = tid & 63;
    const int wm = w >> 2, wn = w & 3;
    const size_t m0 = (size_t)blockIdx.x * 128;
    const size_t n0 = (size_t)blockIdx.y * 256;
    const int klen = K / gridDim.z;
    const int koff = blockIdx.z * klen;
    const int nt = klen >> 6;

    const int p0 = (w * 2) * 64 + lane, p1 = p0 + 64;
    const int sr0 = p0 >> 3, sk0 = ((p0 & 7) ^ (sr0 & 7)) * 8;
    const int sr1 = p1 >> 3, sk1 = ((p1 & 7) ^ (sr1 & 7)) * 8;
    const int scw0 = (w * 2) * 512, scw1 = scw0 + 512;

    auto STAGE = [&](const bf16* g, int ld, size_t row0, int k0, bf16* bufb, int rb) {
        gload_lds16(g + (row0 + sr0) * (size_t)ld + k0 + sk0, bufb + rb + scw0);
        gload_lds16(g + (row0 + sr1) * (size_t)ld + k0 + sk1, bufb + rb + scw1);
    };

    const int fr = lane & 15;
    const int pK0 = (((lane >> 4)) ^ (fr & 7)) * 8;
    const int pK1 = ((4 + (lane >> 4)) ^ (fr & 7)) * 8;
    const size_t aoff = (size_t)(wm * 64 + fr) * 64;
    const size_t boff = 8192 + (size_t)(wn * 64 + fr) * 64;

    f32x4 acc[4][4];
#pragma unroll
    for (int i = 0; i < 4; i++)
#pragma unroll
        for (int j = 0; j < 4; j++)
#pragma unroll
            for (int r = 0; r < 4; r++) acc[i][j][r] = 0.0f;

    bf16x8 aX[2], aY[2], bA[4][2], bB[4][2];

    auto LDA1 = [&](const bf16* lb, int i0, bf16x8 (&d)[2]) {
        d[0] = *(const bf16x8*)(lb + aoff + (size_t)i0 * 1024 + pK0);
        d[1] = *(const bf16x8*)(lb + aoff + (size_t)i0 * 1024 + pK1);
    };
    auto LDB8 = [&](const bf16* lb, bf16x8 (&bb)[4][2]) {
#pragma unroll
        for (int j = 0; j < 4; j++) {
            bb[j][0] = *(const bf16x8*)(lb + boff + j * 1024 + pK0);
            bb[j][1] = *(const bf16x8*)(lb + boff + j * 1024 + pK1);
        }
    };
    auto MM1 = [&](int i0, bf16x8 (&a)[2], bf16x8 (&bb)[4][2]) {
        __builtin_amdgcn_s_setprio(1);
#pragma unroll
        for (int j = 0; j < 4; j++) {
            acc[i0][j] = __builtin_amdgcn_mfma_f32_16x16x32_bf16(a[0], bb[j][0], acc[i0][j], 0, 0, 0);
            acc[i0][j] = __builtin_amdgcn_mfma_f32_16x16x32_bf16(a[1], bb[j][1], acc[i0][j], 0, 0, 0);
        }
        __builtin_amdgcn_s_setprio(0);
    };

    // prologue: tile0 {A,Blo,Bhi} + tile1 {Blo,Bhi} = 10 loads
    STAGE(Ag, lda, m0,       koff,      lds[0], 0);
    STAGE(Bg, ldb, n0,       koff,      lds[0], 8192);
    STAGE(Bg, ldb, n0 + 128, koff,      lds[0], 16384);
    STAGE(Bg, ldb, n0,       koff + 64, lds[1], 8192);
    STAGE(Bg, ldb, n0 + 128, koff + 64, lds[1], 16384);
    asm volatile("s_waitcnt vmcnt(4)");   // tile0 landed
    BARRIER();
    LDB8(lds[0], bA);
    LDA1(lds[0], 0, aX);

    auto tile4 = [&](const bf16* lb, bf16* lbn, bf16x8 (&BU)[4][2], bf16x8 (&BL)[4][2], int t) {
        bf16* lbw = (bf16*)lb;
        LDA1(lb, 1, aY);
        if (t + 1 < nt) STAGE(Ag, lda, m0, koff + ((t + 1) << 6), lbn, 0);
        MM1(0, aX, BU);
        ENDPH();
        LDA1(lb, 2, aX);
        if (t + 2 < nt) STAGE(Bg, ldb, n0, koff + ((t + 2) << 6), lbw, 8192);
        MM1(1, aY, BU);
        ENDPH();
        LDA1(lb, 3, aY);
        if (t + 2 < nt) STAGE(Bg, ldb, n0 + 128, koff + ((t + 2) << 6), lbw, 16384);
        MM1(2, aX, BU);
        __builtin_amdgcn_sched_barrier(0);
        asm volatile("s_waitcnt lgkmcnt(0)");
        __builtin_amdgcn_sched_barrier(0);
        if (t < nt - 2)       { asm volatile("s_waitcnt vmcnt(4)"); }   // A(t+1) landed
        else if (t == nt - 2) { asm volatile("s_waitcnt vmcnt(0)"); }
        BARRIER();
        if (t + 1 < nt) { LDB8(lbn, BL); LDA1(lbn, 0, aX); }
        MM1(3, aY, BU);
        ENDPH();
    };

    for (int t = 0; t < nt; t += 2) {
        tile4(lds[0], lds[1], bA, bB, t);
        tile4(lds[1], lds[0], bB, bA, t + 1);
    }

    const int fq = (lane >> 4) * 4;
#pragma unroll
    for (int i = 0; i < 4; i++)
#pragma unroll
        for (int j = 0; j < 4; j++) {
            size_t cb = n0 + wn * 64 + j * 16 + fr;
            size_t mb = m0 + wm * 64 + i * 16 + fq;
#pragma unroll
            for (int r = 0; r < 4; r++) {
                float v = acc[i][j][r];
                if (MODE == 4) {
                    ((float*)C + blockIdx.z * czs)[(mb + r) * (size_t)ldc + cb] = v;
                } else {
                    ((bf16*)C)[(mb + r) * (size_t)ldc + cb] = (bf16)gelu_f(v);
                }
            }
        }
}

// ---- 128x128 NT GEMM (swizzled LDS) ----
// MODE 4: fp32 store (split-K partial, czs stride).
// CMAP 3: cb<512 -> qb*scale; 512<=cb<1024 -> KVb K-part (ld 512, lat rows);
//         cb>=1024 -> vt transposed (lat rows).
template<int MODE, int CMAP>
__global__ __launch_bounds__(256) void gemm128(const bf16* __restrict__ A, int lda,
                                               const bf16* __restrict__ Bw, int ldb,
                                               void* __restrict__ C, int ldc,
                                               int K, float scale,
                                               long long czs, void* __restrict__ C2,
                                               void* __restrict__ C3) {
    __shared__ bf16 As[128 * 32];
    __shared__ bf16 Bs[128 * 32];
    const int tid = threadIdx.x;
    const int wave = tid >> 6;
    const int lane = tid & 63;
    const size_t m0 = (size_t)blockIdx.x * 128;
    const size_t n0 = (size_t)blockIdx.y * 128;
    const int wm = (wave >> 1) * 64;
    const int wn = (wave & 1) * 64;

    const int klen = K / gridDim.z;
    const int koff = blockIdx.z * klen;

    const int r0 = tid >> 2;
    const int c0 = ((tid & 3) ^ ((tid >> 3) & 3)) * 8;
    const bf16* ga0 = A + (m0 + r0) * lda + c0 + koff;
    const bf16* ga1 = A + (m0 + r0 + 64) * lda + c0 + koff;
    const bf16* gb0 = Bw + (n0 + r0) * ldb + c0 + koff;
    const bf16* gb1 = Bw + (n0 + r0 + 64) * ldb + c0 + koff;
    bf16* la0 = As + wave * 512;
    bf16* la1 = As + 2048 + wave * 512;
    bf16* lb0 = Bs + wave * 512;
    bf16* lb1 = Bs + 2048 + wave * 512;

    f32x4 acc[4][4];
#pragma unroll
    for (int i = 0; i < 4; i++)
#pragma unroll
        for (int j = 0; j < 4; j++)
#pragma unroll
            for (int r = 0; r < 4; r++) acc[i][j][r] = 0.0f;

    const int fr = lane & 15;
    const int q = lane >> 4;
    const int sw = (q ^ ((fr >> 1) & 3)) * 8;

    for (int kt = 0; kt < klen; kt += 32) {
        gload_lds16(ga0 + kt, la0);
        gload_lds16(ga1 + kt, la1);
        gload_lds16(gb0 + kt, lb0);
        gload_lds16(gb1 + kt, lb1);
        __syncthreads();
        bf16x8 af[4], bfv[4];
#pragma unroll
        for (int i = 0; i < 4; i++) {
            af[i]  = *(const bf16x8*)(As + (wm + i * 16 + fr) * 32 + sw);
            bfv[i] = *(const bf16x8*)(Bs + (wn + i * 16 + fr) * 32 + sw);
        }
#pragma unroll
        for (int i = 0; i < 4; i++)
#pragma unroll
            for (int j = 0; j < 4; j++)
                acc[i][j] = __builtin_amdgcn_mfma_f32_16x16x32_bf16(af[i], bfv[j], acc[i][j], 0, 0, 0);
        __syncthreads();
    }

    const int fq = (lane >> 4) * 4;
#pragma unroll
    for (int i = 0; i < 4; i++)
#pragma unroll
        for (int j = 0; j < 4; j++) {
            size_t cb = n0 + wn + j * 16 + fr;
            size_t mb = m0 + wm + i * 16 + fq;
            if (CMAP == 3) {
                if (cb < 512) {
#pragma unroll
                    for (int r = 0; r < 4; r++)
                        ((bf16*)C)[(mb + r) * 512 + cb] = (bf16)(acc[i][j][r] * scale);
                } else if (cb < 1024) {
#pragma unroll
                    for (int r = 0; r < 4; r++) {
                        size_t m = mb + r;
                        size_t rb = (m >> 6) * (size_t)NKV_ + 1024 + (m & 63);
                        ((bf16*)C2)[rb * 512 + (cb - 512)] = (bf16)acc[i][j][r];
                    }
                } else {
                    int hh = ((int)cb - 1024) >> 6, dh = ((int)cb - 1024) & 63;
                    size_t bt = mb >> 6, jl = 1024 + (mb & 63);
                    bf16x4 v4;
#pragma unroll
                    for (int r = 0; r < 4; r++) v4[r] = (bf16)acc[i][j][r];
                    *(bf16x4*)((bf16*)C3 + ((bt * 8 + hh) * 64 + dh) * (size_t)NKV_ + jl) = v4;
                }
            } else {
#pragma unroll
                for (int r = 0; r < 4; r++) {
                    float v = acc[i][j][r];
                    if (MODE == 4) {
                        ((float*)C + blockIdx.z * czs)[(mb + r) * ldc + cb] = v;
                    } else {
                        ((bf16*)C)[(mb + r) * ldc + cb] = (bf16)v;
                    }
                }
            }
        }
}

// ======== fused attention: one block per z + defer-max (THR=8) ========
__global__ __launch_bounds__(256, 2) void attn_k(const bf16* __restrict__ qb,
                                                 const bf16* __restrict__ KVb,
                                                 const bf16* __restrict__ vt,
                                                 bf16* __restrict__ ob) {
    __shared__ float comb[4][64 * 66];
    __shared__ float sc[4][64];
    __shared__ float mw[4][64], lw[4][64];
    const int z = blockIdx.x, bt = z >> 3, h = z & 7;
    const int tid = threadIdx.x, w = tid >> 6, lane = tid & 63;
    const int fr = lane & 15, g = lane >> 4;
    const bf16* Qz = qb + (size_t)(bt * 64) * INNER_ + h * DH_;
    const bf16* Kz = KVb + (size_t)bt * NKV_ * 512 + h * DH_;   // K rows, ld 512
    const bf16* Vz = vt + (size_t)z * (DH_ * NKV_);
    bf16* Pw = (bf16*)(&comb[w][0]);

    bf16x8 qf[4][2];
#pragma unroll
    for (int nj = 0; nj < 4; nj++)
#pragma unroll
        for (int ks = 0; ks < 2; ks++)
            qf[nj][ks] = *(const bf16x8*)(Qz + (size_t)(fr + 16 * nj) * INNER_ + g * 8 + ks * 32);

    f32x4 acc_o[4][4];
#pragma unroll
    for (int i = 0; i < 4; i++)
#pragma unroll
        for (int j = 0; j < 4; j++)
#pragma unroll
            for (int r = 0; r < 4; r++) acc_o[i][j][r] = 0.0f;
    float m_reg[4] = {-INFINITY, -INFINITY, -INFINITY, -INFINITY};
    float l_reg[4] = {0.0f, 0.0f, 0.0f, 0.0f};

    const int nch = (w == 0) ? 5 : 4;
    for (int ci = 0; ci < nch; ci++) {
        const int kc0 = (w + ci * 4) * 64;
        f32x4 s[4][4];
#pragma unroll
        for (int i = 0; i < 4; i++)
#pragma unroll
            for (int j = 0; j < 4; j++)
#pragma unroll
                for (int r = 0; r < 4; r++) s[i][j][r] = 0.0f;
#pragma unroll
        for (int ks = 0; ks < 2; ks++) {
            bf16x8 kf[4];
#pragma unroll
            for (int mi = 0; mi < 4; mi++)
                kf[mi] = *(const bf16x8*)(Kz + (size_t)(kc0 + fr + 16 * mi) * 512 + g * 8 + ks * 32);
#pragma unroll
            for (int mi = 0; mi < 4; mi++)
#pragma unroll
                for (int nj = 0; nj < 4; nj++)
                    s[mi][nj] = __builtin_amdgcn_mfma_f32_16x16x32_bf16(kf[mi], qf[nj][ks], s[mi][nj], 0, 0, 0);
        }
        float pmax[4];
#pragma unroll
        for (int nj = 0; nj < 4; nj++) {
            float mx = s[0][nj][0];
#pragma unroll
            for (int mi = 0; mi < 4; mi++)
#pragma unroll
                for (int r = 0; r < 4; r++) mx = fmaxf(mx, s[mi][nj][r]);
            mx = fmaxf(mx, __shfl_xor(mx, 16, 64));
            mx = fmaxf(mx, __shfl_xor(mx, 32, 64));
            pmax[nj] = mx;
        }
        // defer-max (T13, THR=8): rescale only when growth exceeds 8; P <= e^8
        bool big = (pmax[0] > m_reg[0] + 8.0f) || (pmax[1] > m_reg[1] + 8.0f) ||
                   (pmax[2] > m_reg[2] + 8.0f) || (pmax[3] > m_reg[3] + 8.0f);
        if (__any(big ? 1 : 0)) {
            float so[4];
#pragma unroll
            for (int nj = 0; nj < 4; nj++) {
                float mn = fmaxf(m_reg[nj], pmax[nj]);
                so[nj] = __expf(m_reg[nj] - mn);
                m_reg[nj] = mn;
                l_reg[nj] *= so[nj];
            }
            if (g == 0) {
#pragma unroll
                for (int nj = 0; nj < 4; nj++) sc[w][fr + 16 * nj] = so[nj];
            }
            asm volatile("s_waitcnt lgkmcnt(0)" ::: "memory");
#pragma unroll
            for (int mi = 0; mi < 4; mi++)
#pragma unroll
                for (int r = 0; r < 4; r++) {
                    float sq = sc[w][16 * mi + 4 * g + r];
#pragma unroll
                    for (int jd = 0; jd < 4; jd++) acc_o[mi][jd][r] *= sq;
                }
        }
        float psum[4] = {0.0f, 0.0f, 0.0f, 0.0f};
#pragma unroll
        for (int mi = 0; mi < 4; mi++)
#pragma unroll
            for (int nj = 0; nj < 4; nj++) {
                bf16x4 pb4;
#pragma unroll
                for (int r = 0; r < 4; r++) {
                    float pv = __expf(s[mi][nj][r] - m_reg[nj]);
                    psum[nj] += pv;
                    pb4[r] = (bf16)pv;
                }
                *(bf16x4*)(Pw + (size_t)(fr + 16 * nj) * 72 + 16 * mi + 4 * g) = pb4;
            }
#pragma unroll
        for (int nj = 0; nj < 4; nj++) {
            float ps = psum[nj];
            ps += __shfl_xor(ps, 16, 64);
            ps += __shfl_xor(ps, 32, 64);
            l_reg[nj] += ps;
        }
        asm volatile("s_waitcnt lgkmcnt(0)" ::: "memory");
#pragma unroll
        for (int ks = 0; ks < 2; ks++) {
            bf16x8 af[4], vf[4];
#pragma unroll
            for (int mi = 0; mi < 4; mi++)
                af[mi] = *(const bf16x8*)(Pw + (size_t)(fr + 16 * mi) * 72 + g * 8 + ks * 32);
#pragma unroll
            for (int jd = 0; jd < 4; jd++)
                vf[jd] = *(const bf16x8*)(Vz + (size_t)(fr + 16 * jd) * NKV_ + kc0 + g * 8 + ks * 32);
#pragma unroll
            for (int mi = 0; mi < 4; mi++)
#pragma unroll
                for (int jd = 0; jd < 4; jd++)
                    acc_o[mi][jd] = __builtin_amdgcn_mfma_f32_16x16x32_bf16(af[mi], vf[jd], acc_o[mi][jd], 0, 0, 0);
        }
    }

    if (g == 0) {
#pragma unroll
        for (int nj = 0; nj < 4; nj++) {
            mw[w][fr + 16 * nj] = m_reg[nj];
            lw[w][fr + 16 * nj] = l_reg[nj];
        }
    }
    asm volatile("s_waitcnt lgkmcnt(0)" ::: "memory");
#pragma unroll
    for (int mi = 0; mi < 4; mi++)
#pragma unroll
        for (int jd = 0; jd < 4; jd++)
#pragma unroll
            for (int r = 0; r < 4; r++)
                comb[w][(16 * mi + 4 * g + r) * 66 + fr + 16 * jd] = acc_o[mi][jd][r];
    __syncthreads();
    {
        int q = tid >> 2, d0 = (tid & 3) * 16;
        float M = fmaxf(fmaxf(mw[0][q], mw[1][q]), fmaxf(mw[2][q], mw[3][q]));
        float al[4], l = 0.0f;
#pragma unroll
        for (int ww = 0; ww < 4; ww++) { al[ww] = __expf(mw[ww][q] - M); l += al[ww] * lw[ww][q]; }
        float inv = 1.0f / l;
        bf16 outv[16];
#pragma unroll
        for (int dd = 0; dd < 16; dd++) {
            float o = 0.0f;
#pragma unroll
            for (int ww = 0; ww < 4; ww++) o += comb[ww][q * 66 + d0 + dd] * al[ww];
            outv[dd] = (bf16)(o * inv);
        }
        bf16* dst = ob + (size_t)(bt * 64 + q) * INNER_ + h * 64 + d0;
        *(bf16x8*)dst = *(bf16x8*)outv;
        *(bf16x8*)(dst + 8) = *(bf16x8*)(outv + 8);
    }
}

// ---- host side ----
extern "C" void kernel_launch(void* const* d_in, const int* in_sizes, int n_in,
                              void* d_out, int out_size, void* d_ws, size_t ws_size,
                              hipStream_t stream) {
    const float* x       = (const float*)d_in[0];
    const float* latents = (const float*)d_in[1];
    const float* fe      = (const float*)d_in[2];
    const float* g_media = (const float*)d_in[3];
    const float* b_media = (const float*)d_in[4];
    const float* g_lat   = (const float*)d_in[5];
    const float* b_lat   = (const float*)d_in[6];
    const float* Wq      = (const float*)d_in[7];
    const float* Wkv     = (const float*)d_in[8];
    const float* Wo      = (const float*)d_in[9];
    const float* g_ff    = (const float*)d_in[10];
    const float* b_ff    = (const float*)d_in[11];
    const float* W1      = (const float*)d_in[12];
    const float* W2      = (const float*)d_in[13];
    const float* g_out   = (const float*)d_in[14];
    const float* b_out   = (const float*)d_in[15];

    char* p = (char*)d_ws;
    auto alloc = [&](size_t bytes) { char* r = p; p += (bytes + 255) & ~(size_t)255; return r; };
    bf16*  xhat = (bf16*)alloc((size_t)MROWS_ * D_ * 2);          // 67 MB
    float* lat  = (float*)alloc((size_t)2048 * D_ * 4);           // 8 MB
    bf16*  lnl  = (bf16*)alloc((size_t)2048 * D_ * 2);            // 4 MB
    bf16*  qb   = (bf16*)alloc((size_t)2048 * INNER_ * 2);        // 2 MB
    bf16*  KVb  = (bf16*)alloc((size_t)KVROWS_ * 512 * 2);        // 36 MB (K-part only, ld 512)
    bf16*  vt   = (bf16*)alloc((size_t)ZB_ * DH_ * NKV_ * 2);     // 36 MB
    bf16*  ob   = (bf16*)alloc((size_t)2048 * INNER_ * 2);        // 2 MB
    bf16*  Bcat = (bf16*)alloc((size_t)1536 * D_ * 2);            // 3 MB
    bf16*  WkvTg= (bf16*)alloc((size_t)D_ * D_ * 2);
    bf16*  WoT  = (bf16*)alloc((size_t)D_ * INNER_ * 2);
    bf16*  W1T  = (bf16*)alloc((size_t)FF_ * D_ * 2);
    bf16*  W2T  = (bf16*)alloc((size_t)D_ * FF_ * 2);
    float* bkv  = (float*)alloc(1024 * 4);
    float* ffp  = (float*)alloc((size_t)4 * 2048 * D_ * 4);       // 32 MB
    bf16*  ffh  = vt;            // alias: vt dead once attn done

    xhat_k<<<MROWS_, 256, 0, stream>>>(x, fe, xhat);
    latinit_k<<<2048, 256, 0, stream>>>(latents, lat);
    ln_k<0><<<2048, 256, 0, stream>>>(lat, g_lat, b_lat, lnl);   // layer-0 latent LN

    const long long PS = (long long)2048 * D_;

    for (int l = 0; l < L_; l++) {
        const float* gm = g_media + (size_t)l * D_;
        const float* bm = b_media + (size_t)l * D_;
        const float* gf = g_ff + (size_t)l * D_;
        const float* bf_ = b_ff + (size_t)l * D_;
        const float* wq = Wq + (size_t)l * D_ * INNER_;
        const float* wkv = Wkv + (size_t)l * D_ * 2 * INNER_;
        const float* wo = Wo + (size_t)l * INNER_ * D_;
        const float* w1 = W1 + (size_t)l * D_ * FF_;
        const float* w2 = W2 + (size_t)l * FF_ * D_;

        hipMemsetAsync(bkv, 0, 1024 * 4, stream);
        wprep_k<<<11264, 256, 0, stream>>>(wq, wkv, wo, w1, w2, gm, bm, bkv,
                                           Bcat, Bcat + (size_t)512 * D_, WkvTg, WoT, W1T, W2T);

        // KV x-part: K -> KVb, V -> vt (transposed), +bkv   [8-phase 256², proven]
        gemm_kv<<<dim3(128, 4), 512, 0, stream>>>(xhat, WkvTg, KVb, vt, bkv);
        // merged: q = (lnl@WqT)*scale; KV lat rows: K -> KVb, V -> vt
        gemm128<0, 3><<<dim3(16, 12), 256, 0, stream>>>(
            lnl, D_, Bcat, D_, qb, 0, D_, 0.125f, 0, KVb, vt);

        // fused attention -> ob
        attn_k<<<ZB_, 256, 0, stream>>>(qb, KVb, vt, ob);

        // Wo split-K 2 -> fp32 partials
        gemm128<4, 0><<<dim3(16, 8, 2), 256, 0, stream>>>(
            ob, INNER_, WoT, INNER_, ffp, D_, INNER_, 1.0f, PS, nullptr, nullptr);
        // lat += partials; lnl = LN(lat; gf,bf)
        accln_k<2, 0><<<2048, 256, 0, stream>>>(lat, ffp, PS, gf, bf_, lnl);

        // FF1: ffh = gelu(lnl @ W1T)   [pipelined 128x256]
        gemm_ff<3><<<dim3(16, 16), 512, 0, stream>>>(
            lnl, D_, W1T, D_, ffh, FF_, D_, 0);
        // FF2 split-K 4 -> fp32 partials
        gemm_ff<4><<<dim3(16, 4, 4), 512, 0, stream>>>(
            ffh, FF_, W2T, FF_, ffp, D_, FF_, PS);
        // lat += partials; next-layer latent LN (or final LN -> d_out)
        if (l < L_ - 1) {
            accln_k<4, 0><<<2048, 256, 0, stream>>>(lat, ffp, PS,
                g_lat + (size_t)(l + 1) * D_, b_lat + (size_t)(l + 1) * D_, lnl);
        } else {
            accln_k<4, 1><<<2048, 256, 0, stream>>>(lat, ffp, PS, g_out, b_out, (float*)d_out);
        }
    }
}

// Round 14
// 1268.805 us; speedup vs baseline: 1.1234x; 1.0072x over previous
//
#include <hip/hip_runtime.h>
#include <math.h>

// ---- problem constants ----
#define D_      1024
#define DH_     64
#define H_      8
#define INNER_  512
#define L_      6
#define NL_     64
#define FF_     4096
#define B_      4
#define T_      8
#define FV_     1024          // F*V
#define BT_     32            // B*T
#define MROWS_  32768         // BT*FV
#define NKV_    1088          // FV + NL
#define KVROWS_ 34816         // BT*NKV
#define ZB_     256           // BT*H

typedef __bf16 bf16;
typedef __bf16 bf16x8 __attribute__((ext_vector_type(8)));
typedef __bf16 bf16x4 __attribute__((ext_vector_type(4)));
typedef float  f32x4  __attribute__((ext_vector_type(4)));

#define BARRIER() { asm volatile("" ::: "memory"); __builtin_amdgcn_s_barrier(); asm volatile("" ::: "memory"); }
// end-of-phase (FF pipelined schedule): pin ds_reads above, drain, barrier.
#define ENDPH() { __builtin_amdgcn_sched_barrier(0); asm volatile("s_waitcnt lgkmcnt(0)"); __builtin_amdgcn_sched_barrier(0); BARRIER(); }

// ---- helpers ----
__device__ __forceinline__ void gload_lds16(const bf16* g, bf16* l) {
    __builtin_amdgcn_global_load_lds(
        (const __attribute__((address_space(1))) unsigned int*)g,
        (__attribute__((address_space(3))) unsigned int*)l, 16, 0, 0);
}

__device__ __forceinline__ float wred_sum(float v) {
#pragma unroll
    for (int o = 32; o > 0; o >>= 1) v += __shfl_xor(v, o, 64);
    return v;
}

__device__ __forceinline__ float gelu_f(float x) {
    return 0.5f * x * (1.0f + erff(x * 0.70710678118654752440f));
}

// ---- xhat: LN-normalize (x + frame_embs[t]) once, no affine, bf16 out ----
__global__ __launch_bounds__(256) void xhat_k(const float* __restrict__ x,
                                              const float* __restrict__ fe,
                                              bf16* __restrict__ xhat) {
    __shared__ float red[8];
    int row = blockIdx.x;                // bt*FV + fv
    int t = (row >> 10) & 7;
    const float* xr = x + (size_t)row * D_;
    const float* fr_ = fe + (size_t)t * D_;
    int tid = threadIdx.x, c = tid * 4;
    float4 v = *(const float4*)(xr + c);
    float4 f = *(const float4*)(fr_ + c);
    v.x += f.x; v.y += f.y; v.z += f.z; v.w += f.w;
    float s = v.x + v.y + v.z + v.w;
    float ss = v.x * v.x + v.y * v.y + v.z * v.z + v.w * v.w;
    s = wred_sum(s); ss = wred_sum(ss);
    if ((tid & 63) == 0) { red[tid >> 6] = s; red[4 + (tid >> 6)] = ss; }
    __syncthreads();
    s = red[0] + red[1] + red[2] + red[3];
    ss = red[4] + red[5] + red[6] + red[7];
    float mean = s * (1.0f / D_);
    float rstd = rsqrtf(ss * (1.0f / D_) - mean * mean + 1e-5f);
    bf16x4 o;
    o[0] = (bf16)((v.x - mean) * rstd);
    o[1] = (bf16)((v.y - mean) * rstd);
    o[2] = (bf16)((v.z - mean) * rstd);
    o[3] = (bf16)((v.w - mean) * rstd);
    *(bf16x4*)(xhat + (size_t)row * D_ + c) = o;
}

// ---- lat init ----
__global__ __launch_bounds__(256) void latinit_k(const float* __restrict__ latents,
                                                 float* __restrict__ lat) {
    int row = blockIdx.x;
    int i = row & 63;
    int c = threadIdx.x * 4;
    float4 v = *(const float4*)(latents + (size_t)i * D_ + c);
    *(float4*)(lat + (size_t)row * D_ + c) = v;
}

// ---- row LayerNorm with affine: fp32 in, bf16 out ----
template<int OUTF>
__global__ __launch_bounds__(256) void ln_k(const float* __restrict__ in,
                                            const float* __restrict__ g,
                                            const float* __restrict__ b,
                                            void* __restrict__ out) {
    __shared__ float red[8];
    int row = blockIdx.x;
    const float* x = in + (size_t)row * D_;
    int tid = threadIdx.x, c = tid * 4;
    float4 v = *(const float4*)(x + c);
    float s = v.x + v.y + v.z + v.w;
    float ss = v.x * v.x + v.y * v.y + v.z * v.z + v.w * v.w;
    s = wred_sum(s); ss = wred_sum(ss);
    if ((tid & 63) == 0) { red[tid >> 6] = s; red[4 + (tid >> 6)] = ss; }
    __syncthreads();
    s = red[0] + red[1] + red[2] + red[3];
    ss = red[4] + red[5] + red[6] + red[7];
    float mean = s * (1.0f / D_);
    float rstd = rsqrtf(ss * (1.0f / D_) - mean * mean + 1e-5f);
    float4 gv = *(const float4*)(g + c);
    float4 bv = *(const float4*)(b + c);
    float o0 = (v.x - mean) * rstd * gv.x + bv.x;
    float o1 = (v.y - mean) * rstd * gv.y + bv.y;
    float o2 = (v.z - mean) * rstd * gv.z + bv.z;
    float o3 = (v.w - mean) * rstd * gv.w + bv.w;
    if (OUTF) {
        *(float4*)((float*)out + (size_t)row * D_ + c) = make_float4(o0, o1, o2, o3);
    } else {
        bf16x4 o; o[0] = (bf16)o0; o[1] = (bf16)o1; o[2] = (bf16)o2; o[3] = (bf16)o3;
        *(bf16x4*)((bf16*)out + (size_t)row * D_ + c) = o;
    }
}

// ---- accln: lat += sum of NP partials; LN(lat) -> out ----
template<int NP, int OUTF>
__global__ __launch_bounds__(256) void accln_k(float* __restrict__ lat,
                                               const float* __restrict__ p, long long s,
                                               const float* __restrict__ g,
                                               const float* __restrict__ b,
                                               void* __restrict__ out) {
    __shared__ float red[8];
    int row = blockIdx.x;
    int tid = threadIdx.x, c = tid * 4;
    float* lr = lat + (size_t)row * D_;
    float4 a = *(const float4*)(lr + c);
#pragma unroll
    for (int w = 0; w < NP; w++) {
        float4 x = *(const float4*)(p + (size_t)w * s + (size_t)row * D_ + c);
        a.x += x.x; a.y += x.y; a.z += x.z; a.w += x.w;
    }
    if (!OUTF) *(float4*)(lr + c) = a;
    float sm = a.x + a.y + a.z + a.w;
    float ss = a.x * a.x + a.y * a.y + a.z * a.z + a.w * a.w;
    sm = wred_sum(sm); ss = wred_sum(ss);
    if ((tid & 63) == 0) { red[tid >> 6] = sm; red[4 + (tid >> 6)] = ss; }
    __syncthreads();
    sm = red[0] + red[1] + red[2] + red[3];
    ss = red[4] + red[5] + red[6] + red[7];
    float mean = sm * (1.0f / D_);
    float rstd = rsqrtf(ss * (1.0f / D_) - mean * mean + 1e-5f);
    float4 gv = *(const float4*)(g + c);
    float4 bv = *(const float4*)(b + c);
    float o0 = (a.x - mean) * rstd * gv.x + bv.x;
    float o1 = (a.y - mean) * rstd * gv.y + bv.y;
    float o2 = (a.z - mean) * rstd * gv.z + bv.z;
    float o3 = (a.w - mean) * rstd * gv.w + bv.w;
    if (OUTF) {
        *(float4*)((float*)out + (size_t)row * D_ + c) = make_float4(o0, o1, o2, o3);
    } else {
        bf16x4 o; o[0] = (bf16)o0; o[1] = (bf16)o1; o[2] = (bf16)o2; o[3] = (bf16)o3;
        *(bf16x4*)((bf16*)out + (size_t)row * D_ + c) = o;
    }
}

// ---- fused weight prep (per layer) + bkv accumulation in WkvTg branch ----
__device__ __forceinline__ void wt_tile(const float* __restrict__ in, int R, int C,
                                        bf16* __restrict__ out, int bx, int by,
                                        const float* __restrict__ sc,
                                        const float* __restrict__ bm,
                                        float* __restrict__ bkv) {
    __shared__ float t[32][33];
    int c0 = bx * 32, r0 = by * 32;
    int tx = threadIdx.x & 31, ty = threadIdx.x >> 5;
#pragma unroll
    for (int i = 0; i < 4; i++)
        t[ty + i * 8][tx] = in[(size_t)(r0 + ty + i * 8) * C + c0 + tx];
    __syncthreads();
    float scale = sc ? sc[r0 + tx] : 1.0f;
#pragma unroll
    for (int i = 0; i < 4; i++)
        out[(size_t)(c0 + ty + i * 8) * R + r0 + tx] = (bf16)(t[tx][ty + i * 8] * scale);
    if (bm && ty == 0) {
        float s = 0.0f;
#pragma unroll
        for (int r = 0; r < 32; r++) s += bm[r0 + r] * t[r][tx];
        atomicAdd(&bkv[c0 + tx], s);
    }
}

__global__ __launch_bounds__(256) void wprep_k(const float* __restrict__ wq,
                                               const float* __restrict__ wkv,
                                               const float* __restrict__ wo,
                                               const float* __restrict__ w1,
                                               const float* __restrict__ w2,
                                               const float* __restrict__ gm,
                                               const float* __restrict__ bm,
                                               float* __restrict__ bkv,
                                               bf16* __restrict__ BcatQ,   // rows 0..511
                                               bf16* __restrict__ BcatKV,  // rows 512..1535
                                               bf16* __restrict__ WkvTg,
                                               bf16* __restrict__ WoT,
                                               bf16* __restrict__ W1T,
                                               bf16* __restrict__ W2T) {
    int id = blockIdx.x;
    if (id < 512)            wt_tile(wq, D_, INNER_, BcatQ, id & 15, id >> 4, nullptr, nullptr, nullptr);
    else if (id < 1536)  { int i = id - 512;  wt_tile(wkv, D_, 2 * INNER_, BcatKV, i & 31, i >> 5, nullptr, nullptr, nullptr); }
    else if (id < 2560)  { int i = id - 1536; wt_tile(wkv, D_, 2 * INNER_, WkvTg, i & 31, i >> 5, gm, bm, bkv); }
    else if (id < 3072)  { int i = id - 2560; wt_tile(wo, INNER_, D_, WoT, i & 31, i >> 5, nullptr, nullptr, nullptr); }
    else if (id < 7168)  { int i = id - 3072; wt_tile(w1, D_, FF_, W1T, i & 127, i >> 7, nullptr, nullptr, nullptr); }
    else                 { int i = id - 7168; wt_tile(w2, FF_, D_, W2T, i & 31, i >> 5, nullptr, nullptr, nullptr); }
}

// ======== KV GEMM: 256x256 8-phase pipelined NT (proven schedule) ========
__global__ __launch_bounds__(512, 1) void gemm_kv(const bf16* __restrict__ Ag,
                                                  const bf16* __restrict__ Bg,
                                                  bf16* __restrict__ KVb,
                                                  bf16* __restrict__ vt,
                                                  const float* __restrict__ bias) {
    __shared__ bf16 lds[2][32768];   // [buf][Alo 0 | Ahi 8192 | Blo 16384 | Bhi 24576]
    const int lda = D_, ldb = D_;
    const int tid = threadIdx.x;
    const int w = tid >> 6, lane = tid & 63;
    const int wm = w >> 2, wn = w & 3;
    const size_t m0 = (size_t)blockIdx.x * 256;
    const size_t n0 = (size_t)blockIdx.y * 256;
    const int nt = 16;   // K=1024, BK=64

    const int p0 = (w * 2) * 64 + lane, p1 = p0 + 64;
    const int sr0 = p0 >> 3, sk0 = ((p0 & 7) ^ (sr0 & 7)) * 8;
    const int sr1 = p1 >> 3, sk1 = ((p1 & 7) ^ (sr1 & 7)) * 8;
    const int scw0 = (w * 2) * 512, scw1 = scw0 + 512;

    auto STAGE = [&](const bf16* g, int ld, size_t row0, int k0, bf16* bufb, int rb) {
        gload_lds16(g + (row0 + sr0) * (size_t)ld + k0 + sk0, bufb + rb + scw0);
        gload_lds16(g + (row0 + sr1) * (size_t)ld + k0 + sk1, bufb + rb + scw1);
    };

    const int fr = lane & 15;
    const int pK0 = (((lane >> 4)) ^ (fr & 7)) * 8;
    const int pK1 = ((4 + (lane >> 4)) ^ (fr & 7)) * 8;
    const size_t aoff = (size_t)(wm * 128 + fr) * 64;
    const size_t boff = 16384 + (size_t)(wn * 64 + fr) * 64;

    f32x4 acc[8][4];
#pragma unroll
    for (int i = 0; i < 8; i++)
#pragma unroll
        for (int j = 0; j < 4; j++)
#pragma unroll
            for (int r = 0; r < 4; r++) acc[i][j][r] = 0.0f;

    STAGE(Bg, ldb, n0,       0, lds[0], 16384);
    STAGE(Bg, ldb, n0 + 128, 0, lds[0], 24576);
    STAGE(Ag, lda, m0,       0, lds[0], 0);
    STAGE(Ag, lda, m0 + 128, 0, lds[0], 8192);
    STAGE(Bg, ldb, n0,       64, lds[1], 16384);
    STAGE(Bg, ldb, n0 + 128, 64, lds[1], 24576);
    STAGE(Ag, lda, m0,       64, lds[1], 0);
    asm volatile("s_waitcnt vmcnt(6)");
    BARRIER();

    for (int t = 0; t < nt; ++t) {
        const bf16* lb = lds[t & 1];
        bf16* lbw = lds[t & 1];
        bf16* lbn = lds[(t + 1) & 1];
        const int kt1 = (t + 1) << 6, kt2 = (t + 2) << 6;
        bf16x8 bfr[4][2];

        {
#pragma unroll
            for (int j = 0; j < 4; j++) {
                bfr[j][0] = *(const bf16x8*)(lb + boff + j * 1024 + pK0);
                bfr[j][1] = *(const bf16x8*)(lb + boff + j * 1024 + pK1);
            }
            bf16x8 a00 = *(const bf16x8*)(lb + aoff + 0 * 1024 + pK0);
            bf16x8 a01 = *(const bf16x8*)(lb + aoff + 0 * 1024 + pK1);
            bf16x8 a10 = *(const bf16x8*)(lb + aoff + 1 * 1024 + pK0);
            bf16x8 a11 = *(const bf16x8*)(lb + aoff + 1 * 1024 + pK1);
            if (t + 1 < nt) STAGE(Ag, lda, m0 + 128, kt1, lbn, 8192);
            BARRIER();
            asm volatile("s_waitcnt lgkmcnt(0)");
            __builtin_amdgcn_s_setprio(1);
#pragma unroll
            for (int j = 0; j < 4; j++) {
                acc[0][j] = __builtin_amdgcn_mfma_f32_16x16x32_bf16(a00, bfr[j][0], acc[0][j], 0, 0, 0);
                acc[0][j] = __builtin_amdgcn_mfma_f32_16x16x32_bf16(a01, bfr[j][1], acc[0][j], 0, 0, 0);
                acc[1][j] = __builtin_amdgcn_mfma_f32_16x16x32_bf16(a10, bfr[j][0], acc[1][j], 0, 0, 0);
                acc[1][j] = __builtin_amdgcn_mfma_f32_16x16x32_bf16(a11, bfr[j][1], acc[1][j], 0, 0, 0);
            }
            __builtin_amdgcn_s_setprio(0);
            BARRIER();
        }
        {
            bf16x8 a00 = *(const bf16x8*)(lb + aoff + 2 * 1024 + pK0);
            bf16x8 a01 = *(const bf16x8*)(lb + aoff + 2 * 1024 + pK1);
            bf16x8 a10 = *(const bf16x8*)(lb + aoff + 3 * 1024 + pK0);
            bf16x8 a11 = *(const bf16x8*)(lb + aoff + 3 * 1024 + pK1);
            if (t + 2 < nt) STAGE(Bg, ldb, n0, kt2, lbw, 16384);
            BARRIER();
            asm volatile("s_waitcnt lgkmcnt(0)");
            __builtin_amdgcn_s_setprio(1);
#pragma unroll
            for (int j = 0; j < 4; j++) {
                acc[2][j] = __builtin_amdgcn_mfma_f32_16x16x32_bf16(a00, bfr[j][0], acc[2][j], 0, 0, 0);
                acc[2][j] = __builtin_amdgcn_mfma_f32_16x16x32_bf16(a01, bfr[j][1], acc[2][j], 0, 0, 0);
                acc[3][j] = __builtin_amdgcn_mfma_f32_16x16x32_bf16(a10, bfr[j][0], acc[3][j], 0, 0, 0);
                acc[3][j] = __builtin_amdgcn_mfma_f32_16x16x32_bf16(a11, bfr[j][1], acc[3][j], 0, 0, 0);
            }
            __builtin_amdgcn_s_setprio(0);
            BARRIER();
        }
        {
            bf16x8 a00 = *(const bf16x8*)(lb + aoff + 4 * 1024 + pK0);
            bf16x8 a01 = *(const bf16x8*)(lb + aoff + 4 * 1024 + pK1);
            bf16x8 a10 = *(const bf16x8*)(lb + aoff + 5 * 1024 + pK0);
            bf16x8 a11 = *(const bf16x8*)(lb + aoff + 5 * 1024 + pK1);
            if (t + 2 < nt) STAGE(Bg, ldb, n0 + 128, kt2, lbw, 24576);
            BARRIER();
            asm volatile("s_waitcnt lgkmcnt(0)");
            __builtin_amdgcn_s_setprio(1);
#pragma unroll
            for (int j = 0; j < 4; j++) {
                acc[4][j] = __builtin_amdgcn_mfma_f32_16x16x32_bf16(a00, bfr[j][0], acc[4][j], 0, 0, 0);
                acc[4][j] = __builtin_amdgcn_mfma_f32_16x16x32_bf16(a01, bfr[j][1], acc[4][j], 0, 0, 0);
                acc[5][j] = __builtin_amdgcn_mfma_f32_16x16x32_bf16(a10, bfr[j][0], acc[5][j], 0, 0, 0);
                acc[5][j] = __builtin_amdgcn_mfma_f32_16x16x32_bf16(a11, bfr[j][1], acc[5][j], 0, 0, 0);
            }
            __builtin_amdgcn_s_setprio(0);
            BARRIER();
        }
        {
            bf16x8 a00 = *(const bf16x8*)(lb + aoff + 6 * 1024 + pK0);
            bf16x8 a01 = *(const bf16x8*)(lb + aoff + 6 * 1024 + pK1);
            bf16x8 a10 = *(const bf16x8*)(lb + aoff + 7 * 1024 + pK0);
            bf16x8 a11 = *(const bf16x8*)(lb + aoff + 7 * 1024 + pK1);
            if (t + 2 < nt) STAGE(Ag, lda, m0, kt2, lbw, 0);
            BARRIER();
            asm volatile("s_waitcnt lgkmcnt(0)");
            __builtin_amdgcn_s_setprio(1);
#pragma unroll
            for (int j = 0; j < 4; j++) {
                acc[6][j] = __builtin_amdgcn_mfma_f32_16x16x32_bf16(a00, bfr[j][0], acc[6][j], 0, 0, 0);
                acc[6][j] = __builtin_amdgcn_mfma_f32_16x16x32_bf16(a01, bfr[j][1], acc[6][j], 0, 0, 0);
                acc[7][j] = __builtin_amdgcn_mfma_f32_16x16x32_bf16(a10, bfr[j][0], acc[7][j], 0, 0, 0);
                acc[7][j] = __builtin_amdgcn_mfma_f32_16x16x32_bf16(a11, bfr[j][1], acc[7][j], 0, 0, 0);
            }
            __builtin_amdgcn_s_setprio(0);
            if (t < nt - 2)       { asm volatile("s_waitcnt vmcnt(6)"); }
            else if (t == nt - 2) { asm volatile("s_waitcnt vmcnt(0)"); }
            BARRIER();
        }
    }

    // epilogue: K -> KVb (ld 512), V -> vt transposed
    const int fq = (lane >> 4) * 4;
#pragma unroll
    for (int i = 0; i < 8; i++)
#pragma unroll
        for (int j = 0; j < 4; j++) {
            size_t cb = n0 + wn * 64 + j * 16 + fr;
            float bv = bias[cb];
            size_t mb = m0 + wm * 128 + i * 16 + fq;
            if (cb < 512) {
#pragma unroll
                for (int r = 0; r < 4; r++) {
                    size_t m = mb + r;
                    size_t rb = m + ((m >> 10) << 6);
                    KVb[rb * 512 + cb] = (bf16)(acc[i][j][r] + bv);
                }
            } else {
                int hh = ((int)cb - 512) >> 6, dh = ((int)cb - 512) & 63;
                size_t bt = mb >> 10, jl = mb & 1023;
                bf16x4 v4;
#pragma unroll
                for (int r = 0; r < 4; r++) v4[r] = (bf16)(acc[i][j][r] + bv);
                *(bf16x4*)(vt + ((bt * 8 + hh) * 64 + dh) * (size_t)NKV_ + jl) = v4;
            }
        }
}

// ======== FF GEMM: 128x256, pipelined-frag 4-phase schedule ========
// MODE 3: bf16 gelu out. MODE 4: fp32 split-K partial (czs stride).
template<int MODE>
__global__ __launch_bounds__(512, 1) void gemm_ff(const bf16* __restrict__ Ag, int lda,
                                                  const bf16* __restrict__ Bg, int ldb,
                                                  void* __restrict__ C, int ldc,
                                                  int K, long long czs) {
    __shared__ bf16 lds[2][24576];   // [buf][A 0..8191 | Blo 8192 | Bhi 16384]
    const int tid = threadIdx.x;
    const int w = tid >> 6, lane = tid & 63;
    const int wm = w >> 2, wn = w & 3;
    const size_t m0 = (size_t)blockIdx.x * 128;
    const size_t n0 = (size_t)blockIdx.y * 256;
    const int klen = K / gridDim.z;
    const int koff = blockIdx.z * klen;
    const int nt = klen >> 6;

    const int p0 = (w * 2) * 64 + lane, p1 = p0 + 64;
    const int sr0 = p0 >> 3, sk0 = ((p0 & 7) ^ (sr0 & 7)) * 8;
    const int sr1 = p1 >> 3, sk1 = ((p1 & 7) ^ (sr1 & 7)) * 8;
    const int scw0 = (w * 2) * 512, scw1 = scw0 + 512;

    auto STAGE = [&](const bf16* g, int ld, size_t row0, int k0, bf16* bufb, int rb) {
        gload_lds16(g + (row0 + sr0) * (size_t)ld + k0 + sk0, bufb + rb + scw0);
        gload_lds16(g + (row0 + sr1) * (size_t)ld + k0 + sk1, bufb + rb + scw1);
    };

    const int fr = lane & 15;
    const int pK0 = (((lane >> 4)) ^ (fr & 7)) * 8;
    const int pK1 = ((4 + (lane >> 4)) ^ (fr & 7)) * 8;
    const size_t aoff = (size_t)(wm * 64 + fr) * 64;
    const size_t boff = 8192 + (size_t)(wn * 64 + fr) * 64;

    f32x4 acc[4][4];
#pragma unroll
    for (int i = 0; i < 4; i++)
#pragma unroll
        for (int j = 0; j < 4; j++)
#pragma unroll
            for (int r = 0; r < 4; r++) acc[i][j][r] = 0.0f;

    bf16x8 aX[2], aY[2], bA[4][2], bB[4][2];

    auto LDA1 = [&](const bf16* lb, int i0, bf16x8 (&d)[2]) {
        d[0] = *(const bf16x8*)(lb + aoff + (size_t)i0 * 1024 + pK0);
        d[1] = *(const bf16x8*)(lb + aoff + (size_t)i0 * 1024 + pK1);
    };
    auto LDB8 = [&](const bf16* lb, bf16x8 (&bb)[4][2]) {
#pragma unroll
        for (int j = 0; j < 4; j++) {
            bb[j][0] = *(const bf16x8*)(lb + boff + j * 1024 + pK0);
            bb[j][1] = *(const bf16x8*)(lb + boff + j * 1024 + pK1);
        }
    };
    auto MM1 = [&](int i0, bf16x8 (&a)[2], bf16x8 (&bb)[4][2]) {
        __builtin_amdgcn_s_setprio(1);
#pragma unroll
        for (int j = 0; j < 4; j++) {
            acc[i0][j] = __builtin_amdgcn_mfma_f32_16x16x32_bf16(a[0], bb[j][0], acc[i0][j], 0, 0, 0);
            acc[i0][j] = __builtin_amdgcn_mfma_f32_16x16x32_bf16(a[1], bb[j][1], acc[i0][j], 0, 0, 0);
        }
        __builtin_amdgcn_s_setprio(0);
    };

    // prologue: tile0 {A,Blo,Bhi} + tile1 {Blo,Bhi} = 10 loads
    STAGE(Ag, lda, m0,       koff,      lds[0], 0);
    STAGE(Bg, ldb, n0,       koff,      lds[0], 8192);
    STAGE(Bg, ldb, n0 + 128, koff,      lds[0], 16384);
    STAGE(Bg, ldb, n0,       koff + 64, lds[1], 8192);
    STAGE(Bg, ldb, n0 + 128, koff + 64, lds[1], 16384);
    asm volatile("s_waitcnt vmcnt(4)");   // tile0 landed
    BARRIER();
    LDB8(lds[0], bA);
    LDA1(lds[0], 0, aX);

    auto tile4 = [&](const bf16* lb, bf16* lbn, bf16x8 (&BU)[4][2], bf16x8 (&BL)[4][2], int t) {
        bf16* lbw = (bf16*)lb;
        LDA1(lb, 1, aY);
        if (t + 1 < nt) STAGE(Ag, lda, m0, koff + ((t + 1) << 6), lbn, 0);
        MM1(0, aX, BU);
        ENDPH();
        LDA1(lb, 2, aX);
        if (t + 2 < nt) STAGE(Bg, ldb, n0, koff + ((t + 2) << 6), lbw, 8192);
        MM1(1, aY, BU);
        ENDPH();
        LDA1(lb, 3, aY);
        if (t + 2 < nt) STAGE(Bg, ldb, n0 + 128, koff + ((t + 2) << 6), lbw, 16384);
        MM1(2, aX, BU);
        __builtin_amdgcn_sched_barrier(0);
        asm volatile("s_waitcnt lgkmcnt(0)");
        __builtin_amdgcn_sched_barrier(0);
        if (t < nt - 2)       { asm volatile("s_waitcnt vmcnt(4)"); }   // A(t+1) landed
        else if (t == nt - 2) { asm volatile("s_waitcnt vmcnt(0)"); }
        BARRIER();
        if (t + 1 < nt) { LDB8(lbn, BL); LDA1(lbn, 0, aX); }
        MM1(3, aY, BU);
        ENDPH();
    };

    for (int t = 0; t < nt; t += 2) {
        tile4(lds[0], lds[1], bA, bB, t);
        tile4(lds[1], lds[0], bB, bA, t + 1);
    }

    const int fq = (lane >> 4) * 4;
#pragma unroll
    for (int i = 0; i < 4; i++)
#pragma unroll
        for (int j = 0; j < 4; j++) {
            size_t cb = n0 + wn * 64 + j * 16 + fr;
            size_t mb = m0 + wm * 64 + i * 16 + fq;
#pragma unroll
            for (int r = 0; r < 4; r++) {
                float v = acc[i][j][r];
                if (MODE == 4) {
                    ((float*)C + blockIdx.z * czs)[(mb + r) * (size_t)ldc + cb] = v;
                } else {
                    ((bf16*)C)[(mb + r) * (size_t)ldc + cb] = (bf16)gelu_f(v);
                }
            }
        }
}

// ---- 128x128 NT GEMM (swizzled LDS) ----
// MODE 4: fp32 store (split-K partial, czs stride).
// CMAP 3: cb<512 -> qb*scale; 512<=cb<1024 -> KVb K-part (ld 512, lat rows);
//         cb>=1024 -> vt transposed (lat rows).
template<int MODE, int CMAP>
__global__ __launch_bounds__(256) void gemm128(const bf16* __restrict__ A, int lda,
                                               const bf16* __restrict__ Bw, int ldb,
                                               void* __restrict__ C, int ldc,
                                               int K, float scale,
                                               long long czs, void* __restrict__ C2,
                                               void* __restrict__ C3) {
    __shared__ bf16 As[128 * 32];
    __shared__ bf16 Bs[128 * 32];
    const int tid = threadIdx.x;
    const int wave = tid >> 6;
    const int lane = tid & 63;
    const size_t m0 = (size_t)blockIdx.x * 128;
    const size_t n0 = (size_t)blockIdx.y * 128;
    const int wm = (wave >> 1) * 64;
    const int wn = (wave & 1) * 64;

    const int klen = K / gridDim.z;
    const int koff = blockIdx.z * klen;

    const int r0 = tid >> 2;
    const int c0 = ((tid & 3) ^ ((tid >> 3) & 3)) * 8;
    const bf16* ga0 = A + (m0 + r0) * lda + c0 + koff;
    const bf16* ga1 = A + (m0 + r0 + 64) * lda + c0 + koff;
    const bf16* gb0 = Bw + (n0 + r0) * ldb + c0 + koff;
    const bf16* gb1 = Bw + (n0 + r0 + 64) * ldb + c0 + koff;
    bf16* la0 = As + wave * 512;
    bf16* la1 = As + 2048 + wave * 512;
    bf16* lb0 = Bs + wave * 512;
    bf16* lb1 = Bs + 2048 + wave * 512;

    f32x4 acc[4][4];
#pragma unroll
    for (int i = 0; i < 4; i++)
#pragma unroll
        for (int j = 0; j < 4; j++)
#pragma unroll
            for (int r = 0; r < 4; r++) acc[i][j][r] = 0.0f;

    const int fr = lane & 15;
    const int q = lane >> 4;
    const int sw = (q ^ ((fr >> 1) & 3)) * 8;

    for (int kt = 0; kt < klen; kt += 32) {
        gload_lds16(ga0 + kt, la0);
        gload_lds16(ga1 + kt, la1);
        gload_lds16(gb0 + kt, lb0);
        gload_lds16(gb1 + kt, lb1);
        __syncthreads();
        bf16x8 af[4], bfv[4];
#pragma unroll
        for (int i = 0; i < 4; i++) {
            af[i]  = *(const bf16x8*)(As + (wm + i * 16 + fr) * 32 + sw);
            bfv[i] = *(const bf16x8*)(Bs + (wn + i * 16 + fr) * 32 + sw);
        }
#pragma unroll
        for (int i = 0; i < 4; i++)
#pragma unroll
            for (int j = 0; j < 4; j++)
                acc[i][j] = __builtin_amdgcn_mfma_f32_16x16x32_bf16(af[i], bfv[j], acc[i][j], 0, 0, 0);
        __syncthreads();
    }

    const int fq = (lane >> 4) * 4;
#pragma unroll
    for (int i = 0; i < 4; i++)
#pragma unroll
        for (int j = 0; j < 4; j++) {
            size_t cb = n0 + wn + j * 16 + fr;
            size_t mb = m0 + wm + i * 16 + fq;
            if (CMAP == 3) {
                if (cb < 512) {
#pragma unroll
                    for (int r = 0; r < 4; r++)
                        ((bf16*)C)[(mb + r) * 512 + cb] = (bf16)(acc[i][j][r] * scale);
                } else if (cb < 1024) {
#pragma unroll
                    for (int r = 0; r < 4; r++) {
                        size_t m = mb + r;
                        size_t rb = (m >> 6) * (size_t)NKV_ + 1024 + (m & 63);
                        ((bf16*)C2)[rb * 512 + (cb - 512)] = (bf16)acc[i][j][r];
                    }
                } else {
                    int hh = ((int)cb - 1024) >> 6, dh = ((int)cb - 1024) & 63;
                    size_t bt = mb >> 6, jl = 1024 + (mb & 63);
                    bf16x4 v4;
#pragma unroll
                    for (int r = 0; r < 4; r++) v4[r] = (bf16)acc[i][j][r];
                    *(bf16x4*)((bf16*)C3 + ((bt * 8 + hh) * 64 + dh) * (size_t)NKV_ + jl) = v4;
                }
            } else {
#pragma unroll
                for (int r = 0; r < 4; r++) {
                    float v = acc[i][j][r];
                    if (MODE == 4) {
                        ((float*)C + blockIdx.z * czs)[(mb + r) * ldc + cb] = v;
                    } else {
                        ((bf16*)C)[(mb + r) * ldc + cb] = (bf16)v;
                    }
                }
            }
        }
}

// ======== fused attention: one block per z + defer-max (THR=8) ========
__global__ __launch_bounds__(256, 2) void attn_k(const bf16* __restrict__ qb,
                                                 const bf16* __restrict__ KVb,
                                                 const bf16* __restrict__ vt,
                                                 bf16* __restrict__ ob) {
    __shared__ float comb[4][64 * 66];
    __shared__ float sc[4][64];
    __shared__ float mw[4][64], lw[4][64];
    const int z = blockIdx.x, bt = z >> 3, h = z & 7;
    const int tid = threadIdx.x, w = tid >> 6, lane = tid & 63;
    const int fr = lane & 15, g = lane >> 4;
    const bf16* Qz = qb + (size_t)(bt * 64) * INNER_ + h * DH_;
    const bf16* Kz = KVb + (size_t)bt * NKV_ * 512 + h * DH_;   // K rows, ld 512
    const bf16* Vz = vt + (size_t)z * (DH_ * NKV_);
    bf16* Pw = (bf16*)(&comb[w][0]);

    bf16x8 qf[4][2];
#pragma unroll
    for (int nj = 0; nj < 4; nj++)
#pragma unroll
        for (int ks = 0; ks < 2; ks++)
            qf[nj][ks] = *(const bf16x8*)(Qz + (size_t)(fr + 16 * nj) * INNER_ + g * 8 + ks * 32);

    f32x4 acc_o[4][4];
#pragma unroll
    for (int i = 0; i < 4; i++)
#pragma unroll
        for (int j = 0; j < 4; j++)
#pragma unroll
            for (int r = 0; r < 4; r++) acc_o[i][j][r] = 0.0f;
    float m_reg[4] = {-INFINITY, -INFINITY, -INFINITY, -INFINITY};
    float l_reg[4] = {0.0f, 0.0f, 0.0f, 0.0f};

    const int nch = (w == 0) ? 5 : 4;
    for (int ci = 0; ci < nch; ci++) {
        const int kc0 = (w + ci * 4) * 64;
        f32x4 s[4][4];
#pragma unroll
        for (int i = 0; i < 4; i++)
#pragma unroll
            for (int j = 0; j < 4; j++)
#pragma unroll
                for (int r = 0; r < 4; r++) s[i][j][r] = 0.0f;
#pragma unroll
        for (int ks = 0; ks < 2; ks++) {
            bf16x8 kf[4];
#pragma unroll
            for (int mi = 0; mi < 4; mi++)
                kf[mi] = *(const bf16x8*)(Kz + (size_t)(kc0 + fr + 16 * mi) * 512 + g * 8 + ks * 32);
#pragma unroll
            for (int mi = 0; mi < 4; mi++)
#pragma unroll
                for (int nj = 0; nj < 4; nj++)
                    s[mi][nj] = __builtin_amdgcn_mfma_f32_16x16x32_bf16(kf[mi], qf[nj][ks], s[mi][nj], 0, 0, 0);
        }
        float pmax[4];
#pragma unroll
        for (int nj = 0; nj < 4; nj++) {
            float mx = s[0][nj][0];
#pragma unroll
            for (int mi = 0; mi < 4; mi++)
#pragma unroll
                for (int r = 0; r < 4; r++) mx = fmaxf(mx, s[mi][nj][r]);
            mx = fmaxf(mx, __shfl_xor(mx, 16, 64));
            mx = fmaxf(mx, __shfl_xor(mx, 32, 64));
            pmax[nj] = mx;
        }
        // defer-max (T13, THR=8): rescale only when growth exceeds 8; P <= e^8
        bool big = (pmax[0] > m_reg[0] + 8.0f) || (pmax[1] > m_reg[1] + 8.0f) ||
                   (pmax[2] > m_reg[2] + 8.0f) || (pmax[3] > m_reg[3] + 8.0f);
        if (__any(big ? 1 : 0)) {
            float so[4];
#pragma unroll
            for (int nj = 0; nj < 4; nj++) {
                float mn = fmaxf(m_reg[nj], pmax[nj]);
                so[nj] = __expf(m_reg[nj] - mn);
                m_reg[nj] = mn;
                l_reg[nj] *= so[nj];
            }
            if (g == 0) {
#pragma unroll
                for (int nj = 0; nj < 4; nj++) sc[w][fr + 16 * nj] = so[nj];
            }
            asm volatile("s_waitcnt lgkmcnt(0)" ::: "memory");
#pragma unroll
            for (int mi = 0; mi < 4; mi++)
#pragma unroll
                for (int r = 0; r < 4; r++) {
                    float sq = sc[w][16 * mi + 4 * g + r];
#pragma unroll
                    for (int jd = 0; jd < 4; jd++) acc_o[mi][jd][r] *= sq;
                }
        }
        float psum[4] = {0.0f, 0.0f, 0.0f, 0.0f};
#pragma unroll
        for (int mi = 0; mi < 4; mi++)
#pragma unroll
            for (int nj = 0; nj < 4; nj++) {
                bf16x4 pb4;
#pragma unroll
                for (int r = 0; r < 4; r++) {
                    float pv = __expf(s[mi][nj][r] - m_reg[nj]);
                    psum[nj] += pv;
                    pb4[r] = (bf16)pv;
                }
                *(bf16x4*)(Pw + (size_t)(fr + 16 * nj) * 72 + 16 * mi + 4 * g) = pb4;
            }
#pragma unroll
        for (int nj = 0; nj < 4; nj++) {
            float ps = psum[nj];
            ps += __shfl_xor(ps, 16, 64);
            ps += __shfl_xor(ps, 32, 64);
            l_reg[nj] += ps;
        }
        asm volatile("s_waitcnt lgkmcnt(0)" ::: "memory");
#pragma unroll
        for (int ks = 0; ks < 2; ks++) {
            bf16x8 af[4], vf[4];
#pragma unroll
            for (int mi = 0; mi < 4; mi++)
                af[mi] = *(const bf16x8*)(Pw + (size_t)(fr + 16 * mi) * 72 + g * 8 + ks * 32);
#pragma unroll
            for (int jd = 0; jd < 4; jd++)
                vf[jd] = *(const bf16x8*)(Vz + (size_t)(fr + 16 * jd) * NKV_ + kc0 + g * 8 + ks * 32);
#pragma unroll
            for (int mi = 0; mi < 4; mi++)
#pragma unroll
                for (int jd = 0; jd < 4; jd++)
                    acc_o[mi][jd] = __builtin_amdgcn_mfma_f32_16x16x32_bf16(af[mi], vf[jd], acc_o[mi][jd], 0, 0, 0);
        }
    }

    if (g == 0) {
#pragma unroll
        for (int nj = 0; nj < 4; nj++) {
            mw[w][fr + 16 * nj] = m_reg[nj];
            lw[w][fr + 16 * nj] = l_reg[nj];
        }
    }
    asm volatile("s_waitcnt lgkmcnt(0)" ::: "memory");
#pragma unroll
    for (int mi = 0; mi < 4; mi++)
#pragma unroll
        for (int jd = 0; jd < 4; jd++)
#pragma unroll
            for (int r = 0; r < 4; r++)
                comb[w][(16 * mi + 4 * g + r) * 66 + fr + 16 * jd] = acc_o[mi][jd][r];
    __syncthreads();
    {
        int q = tid >> 2, d0 = (tid & 3) * 16;
        float M = fmaxf(fmaxf(mw[0][q], mw[1][q]), fmaxf(mw[2][q], mw[3][q]));
        float al[4], l = 0.0f;
#pragma unroll
        for (int ww = 0; ww < 4; ww++) { al[ww] = __expf(mw[ww][q] - M); l += al[ww] * lw[ww][q]; }
        float inv = 1.0f / l;
        bf16 outv[16];
#pragma unroll
        for (int dd = 0; dd < 16; dd++) {
            float o = 0.0f;
#pragma unroll
            for (int ww = 0; ww < 4; ww++) o += comb[ww][q * 66 + d0 + dd] * al[ww];
            outv[dd] = (bf16)(o * inv);
        }
        bf16* dst = ob + (size_t)(bt * 64 + q) * INNER_ + h * 64 + d0;
        *(bf16x8*)dst = *(bf16x8*)outv;
        *(bf16x8*)(dst + 8) = *(bf16x8*)(outv + 8);
    }
}

// ---- host side ----
extern "C" void kernel_launch(void* const* d_in, const int* in_sizes, int n_in,
                              void* d_out, int out_size, void* d_ws, size_t ws_size,
                              hipStream_t stream) {
    const float* x       = (const float*)d_in[0];
    const float* latents = (const float*)d_in[1];
    const float* fe      = (const float*)d_in[2];
    const float* g_media = (const float*)d_in[3];
    const float* b_media = (const float*)d_in[4];
    const float* g_lat   = (const float*)d_in[5];
    const float* b_lat   = (const float*)d_in[6];
    const float* Wq      = (const float*)d_in[7];
    const float* Wkv     = (const float*)d_in[8];
    const float* Wo      = (const float*)d_in[9];
    const float* g_ff    = (const float*)d_in[10];
    const float* b_ff    = (const float*)d_in[11];
    const float* W1      = (const float*)d_in[12];
    const float* W2      = (const float*)d_in[13];
    const float* g_out   = (const float*)d_in[14];
    const float* b_out   = (const float*)d_in[15];

    char* p = (char*)d_ws;
    auto alloc = [&](size_t bytes) { char* r = p; p += (bytes + 255) & ~(size_t)255; return r; };
    bf16*  xhat = (bf16*)alloc((size_t)MROWS_ * D_ * 2);          // 67 MB
    float* lat  = (float*)alloc((size_t)2048 * D_ * 4);           // 8 MB
    bf16*  lnl  = (bf16*)alloc((size_t)2048 * D_ * 2);            // 4 MB
    bf16*  qb   = (bf16*)alloc((size_t)2048 * INNER_ * 2);        // 2 MB
    bf16*  KVb  = (bf16*)alloc((size_t)KVROWS_ * 512 * 2);        // 36 MB (K-part only, ld 512)
    bf16*  vt   = (bf16*)alloc((size_t)ZB_ * DH_ * NKV_ * 2);     // 36 MB
    bf16*  ob   = (bf16*)alloc((size_t)2048 * INNER_ * 2);        // 2 MB
    bf16*  Bcat = (bf16*)alloc((size_t)1536 * D_ * 2);            // 3 MB
    bf16*  WkvTg= (bf16*)alloc((size_t)D_ * D_ * 2);
    bf16*  WoT  = (bf16*)alloc((size_t)D_ * INNER_ * 2);
    bf16*  W1T  = (bf16*)alloc((size_t)FF_ * D_ * 2);
    bf16*  W2T  = (bf16*)alloc((size_t)D_ * FF_ * 2);
    float* bkv6 = (float*)alloc((size_t)L_ * 1024 * 4);           // per-layer bias slices
    float* ffp  = (float*)alloc((size_t)4 * 2048 * D_ * 4);       // 32 MB
    bf16*  ffh  = vt;            // alias: vt dead once attn done

    xhat_k<<<MROWS_, 256, 0, stream>>>(x, fe, xhat);
    latinit_k<<<2048, 256, 0, stream>>>(latents, lat);
    ln_k<0><<<2048, 256, 0, stream>>>(lat, g_lat, b_lat, lnl);   // layer-0 latent LN
    hipMemsetAsync(bkv6, 0, (size_t)L_ * 1024 * 4, stream);      // one memset for all layers

    const long long PS = (long long)2048 * D_;

    for (int l = 0; l < L_; l++) {
        const float* gm = g_media + (size_t)l * D_;
        const float* bm = b_media + (size_t)l * D_;
        const float* gf = g_ff + (size_t)l * D_;
        const float* bf_ = b_ff + (size_t)l * D_;
        const float* wq = Wq + (size_t)l * D_ * INNER_;
        const float* wkv = Wkv + (size_t)l * D_ * 2 * INNER_;
        const float* wo = Wo + (size_t)l * INNER_ * D_;
        const float* w1 = W1 + (size_t)l * D_ * FF_;
        const float* w2 = W2 + (size_t)l * FF_ * D_;
        float* bkv = bkv6 + (size_t)l * 1024;

        wprep_k<<<11264, 256, 0, stream>>>(wq, wkv, wo, w1, w2, gm, bm, bkv,
                                           Bcat, Bcat + (size_t)512 * D_, WkvTg, WoT, W1T, W2T);

        // KV x-part: K -> KVb, V -> vt (transposed), +bkv   [8-phase 256², proven]
        gemm_kv<<<dim3(128, 4), 512, 0, stream>>>(xhat, WkvTg, KVb, vt, bkv);
        // merged: q = (lnl@WqT)*scale; KV lat rows: K -> KVb, V -> vt
        gemm128<0, 3><<<dim3(16, 12), 256, 0, stream>>>(
            lnl, D_, Bcat, D_, qb, 0, D_, 0.125f, 0, KVb, vt);

        // fused attention -> ob
        attn_k<<<ZB_, 256, 0, stream>>>(qb, KVb, vt, ob);

        // Wo split-K 2 -> fp32 partials
        gemm128<4, 0><<<dim3(16, 8, 2), 256, 0, stream>>>(
            ob, INNER_, WoT, INNER_, ffp, D_, INNER_, 1.0f, PS, nullptr, nullptr);
        // lat += partials; lnl = LN(lat; gf,bf)
        accln_k<2, 0><<<2048, 256, 0, stream>>>(lat, ffp, PS, gf, bf_, lnl);

        // FF1: ffh = gelu(lnl @ W1T)   [pipelined 128x256]
        gemm_ff<3><<<dim3(16, 16), 512, 0, stream>>>(
            lnl, D_, W1T, D_, ffh, FF_, D_, 0);
        // FF2 split-K 4 -> fp32 partials
        gemm_ff<4><<<dim3(16, 4, 4), 512, 0, stream>>>(
            ffh, FF_, W2T, FF_, ffp, D_, FF_, PS);
        // lat += partials; next-layer latent LN (or final LN -> d_out)
        if (l < L_ - 1) {
            accln_k<4, 0><<<2048, 256, 0, stream>>>(lat, ffp, PS,
                g_lat + (size_t)(l + 1) * D_, b_lat + (size_t)(l + 1) * D_, lnl);
        } else {
            accln_k<4, 1><<<2048, 256, 0, stream>>>(lat, ffp, PS, g_out, b_out, (float*)d_out);
        }
    }
}